// Round 1
// baseline (529.769 us; speedup 1.0000x reference)
//
#include <hip/hip_runtime.h>
#include <math.h>

#define NT 4096
#define NS 2048
#define DDIM 512
#define KN 5

// ---------------------------------------------------------------- k_init
__global__ __launch_bounds__(256) void k_init(unsigned* __restrict__ hists,
                                              unsigned* __restrict__ sel)
{
    for (int i = threadIdx.x; i < 11264; i += 256) hists[i] = 0;
    if (threadIdx.x == 0) {
        // 0-based ranks of the two middle elements of M = 4096*4095
        sel[0] = 0u; sel[1] = 8386559u;   // target A: prefix, remaining rank
        sel[2] = 0u; sel[3] = 8386560u;   // target B
    }
}

// ---------------------------------------------------------------- k_norms
__global__ __launch_bounds__(64) void k_norms(const float* __restrict__ S,
                                              const float* __restrict__ T,
                                              float* __restrict__ norms)
{
    int r = blockIdx.x;
    int lane = threadIdx.x;
    const float* row = (r < NS) ? S + (size_t)r * DDIM : T + (size_t)(r - NS) * DDIM;
    float4 v1 = *(const float4*)(row + lane * 8);
    float4 v2 = *(const float4*)(row + lane * 8 + 4);
    float s = v1.x*v1.x + v1.y*v1.y + v1.z*v1.z + v1.w*v1.w
            + v2.x*v2.x + v2.y*v2.y + v2.z*v2.z + v2.w*v2.w;
    #pragma unroll
    for (int m = 32; m > 0; m >>= 1) s += __shfl_xor(s, m);
    if (lane == 0) norms[r] = s;
}

// ---------------------------------------------------------------- k_dist
// D[i][j] = max(n_i + n_j - 2 * dot(row_i, row_j), 0)  (fp32, 64x64 tiles)
__global__ __launch_bounds__(256) void k_dist(const float* __restrict__ S,
                                              const float* __restrict__ T,
                                              const float* __restrict__ norms,
                                              float* __restrict__ D)
{
    __shared__ __align__(16) float sA[16][68];
    __shared__ __align__(16) float sB[16][68];
    const int tid = threadIdx.x;
    const int tx = tid & 15, ty = tid >> 4;
    const int m0 = blockIdx.y * 64, n0 = blockIdx.x * 64;
    const int lrow = tid >> 2;          // 0..63
    const int lk = (tid & 3) * 4;       // 0,4,8,12
    const int ar = m0 + lrow, br = n0 + lrow;
    const float* arow = (ar < NS) ? S + (size_t)ar * DDIM : T + (size_t)(ar - NS) * DDIM;
    const float* brow = (br < NS) ? S + (size_t)br * DDIM : T + (size_t)(br - NS) * DDIM;
    float acc[4][4] = {};
    for (int k0 = 0; k0 < DDIM; k0 += 16) {
        float4 va = *(const float4*)(arow + k0 + lk);
        float4 vb = *(const float4*)(brow + k0 + lk);
        __syncthreads();
        sA[lk+0][lrow] = va.x; sA[lk+1][lrow] = va.y; sA[lk+2][lrow] = va.z; sA[lk+3][lrow] = va.w;
        sB[lk+0][lrow] = vb.x; sB[lk+1][lrow] = vb.y; sB[lk+2][lrow] = vb.z; sB[lk+3][lrow] = vb.w;
        __syncthreads();
        #pragma unroll
        for (int kk = 0; kk < 16; ++kk) {
            float4 a = *(const float4*)&sA[kk][ty * 4];
            float4 b = *(const float4*)&sB[kk][tx * 4];
            acc[0][0] += a.x*b.x; acc[0][1] += a.x*b.y; acc[0][2] += a.x*b.z; acc[0][3] += a.x*b.w;
            acc[1][0] += a.y*b.x; acc[1][1] += a.y*b.y; acc[1][2] += a.y*b.z; acc[1][3] += a.y*b.w;
            acc[2][0] += a.z*b.x; acc[2][1] += a.z*b.y; acc[2][2] += a.z*b.z; acc[2][3] += a.z*b.w;
            acc[3][0] += a.w*b.x; acc[3][1] += a.w*b.y; acc[3][2] += a.w*b.z; acc[3][3] += a.w*b.w;
        }
    }
    #pragma unroll
    for (int i = 0; i < 4; ++i) {
        int r = m0 + ty * 4 + i;
        float nr = norms[r];
        float4 o;
        o.x = fmaxf(nr + norms[n0 + tx*4 + 0] - 2.0f * acc[i][0], 0.0f);
        o.y = fmaxf(nr + norms[n0 + tx*4 + 1] - 2.0f * acc[i][1], 0.0f);
        o.z = fmaxf(nr + norms[n0 + tx*4 + 2] - 2.0f * acc[i][2], 0.0f);
        o.w = fmaxf(nr + norms[n0 + tx*4 + 3] - 2.0f * acc[i][3], 0.0f);
        *(float4*)&D[(size_t)r * NT + n0 + tx * 4] = o;
    }
}

// ---------------------------------------------------------------- k_gmat
// per-pair bandwidth (median of 6 pair distances) and g[p][k]
__global__ __launch_bounds__(64) void k_gmat(const float* __restrict__ S,
                                             const float* __restrict__ T,
                                             float* __restrict__ g)
{
    int p = blockIdx.x;
    int lane = threadIdx.x;
    const float* a = S + (size_t)(2 * p) * DDIM;
    const float* b = S + (size_t)(2 * p + 1) * DDIM;
    const float* c = T + (size_t)(2 * p) * DDIM;
    const float* d = T + (size_t)(2 * p + 1) * DDIM;
    float s01 = 0, s23 = 0, s02 = 0, s13 = 0, s03 = 0, s12 = 0;
    for (int k = lane; k < DDIM; k += 64) {
        float va = a[k], vb = b[k], vc = c[k], vd = d[k];
        float t01 = va - vb, t23 = vc - vd, t02 = va - vc, t13 = vb - vd, t03 = va - vd, t12 = vb - vc;
        s01 += t01*t01; s23 += t23*t23; s02 += t02*t02;
        s13 += t13*t13; s03 += t03*t03; s12 += t12*t12;
    }
    #pragma unroll
    for (int m = 32; m > 0; m >>= 1) {
        s01 += __shfl_xor(s01, m); s23 += __shfl_xor(s23, m);
        s02 += __shfl_xor(s02, m); s13 += __shfl_xor(s13, m);
        s03 += __shfl_xor(s03, m); s12 += __shfl_xor(s12, m);
    }
    if (lane == 0) {
        float v[6] = { s01, s02, s03, s12, s13, s23 };
        for (int i = 0; i < 5; ++i)
            for (int j = 0; j < 5 - i; ++j)
                if (v[j] > v[j + 1]) { float t = v[j]; v[j] = v[j + 1]; v[j + 1] = t; }
        // median of the 12 offdiag values (each pair dist twice) = (d3+d4)/2 of 6 sorted
        float med = 0.5f * (v[2] + v[3]);
        float bw = (med + 1e-6f) * 0.25f;   // / KERNEL_MUL^(KERNEL_NUM//2) = /4
        #pragma unroll
        for (int k = 0; k < KN; ++k) {
            float inv = 1.0f / (bw * (float)(1 << k));
            g[(size_t)p * KN + k] = expf(-s01 * inv) + expf(-s23 * inv)
                                  - expf(-s02 * inv) - expf(-s13 * inv);
        }
    }
}

// ---------------------------------------------------------------- k_beta
__global__ __launch_bounds__(64) void k_beta(const float* __restrict__ g,
                                             const float* __restrict__ beta_in,
                                             float* __restrict__ beta_out)
{
    int lane = threadIdx.x;
    float gs[KN] = {0, 0, 0, 0, 0};
    float gg[15];
    #pragma unroll
    for (int i = 0; i < 15; ++i) gg[i] = 0.0f;
    for (int p = lane; p < 1024; p += 64) {
        float gv[KN];
        #pragma unroll
        for (int k = 0; k < KN; ++k) gv[k] = g[(size_t)p * KN + k];
        int idx = 0;
        #pragma unroll
        for (int a2 = 0; a2 < KN; ++a2) {
            gs[a2] += gv[a2];
            #pragma unroll
            for (int b2 = a2; b2 < KN; ++b2) gg[idx++] += gv[a2] * gv[b2];
        }
    }
    #pragma unroll
    for (int m = 32; m > 0; m >>= 1) {
        #pragma unroll
        for (int k = 0; k < KN; ++k) gs[k] += __shfl_xor(gs[k], m);
        #pragma unroll
        for (int i = 0; i < 15; ++i) gg[i] += __shfl_xor(gg[i], m);
    }
    if (lane == 0) {
        float Q[KN][KN], gm[KN];
        #pragma unroll
        for (int k = 0; k < KN; ++k) gm[k] = gs[k] * (1.0f / 1024.0f);
        int idx = 0;
        for (int a2 = 0; a2 < KN; ++a2)
            for (int b2 = a2; b2 < KN; ++b2) {
                float q = gg[idx++] * (1.0f / 1024.0f) - gm[a2] * gm[b2];
                Q[a2][b2] = q; Q[b2][a2] = q;
            }
        for (int k = 0; k < KN; ++k) Q[k][k] += 0.001f;

        float b[KN], proj[KN];
        for (int k = 0; k < KN; ++k) { b[k] = beta_in[k]; proj[k] = b[k]; }
        for (int it = 0; it < 100; ++it) {
            float v[KN];
            for (int a2 = 0; a2 < KN; ++a2) {
                float qb = 0;
                for (int b2 = 0; b2 < KN; ++b2) qb += Q[a2][b2] * b[b2];
                v[a2] = b[a2] - qb;
            }
            float mu[KN];
            for (int k = 0; k < KN; ++k) mu[k] = v[k];
            for (int i = 0; i < KN - 1; ++i)            // descending sort
                for (int j = 0; j < KN - 1 - i; ++j)
                    if (mu[j] < mu[j + 1]) { float t = mu[j]; mu[j] = mu[j + 1]; mu[j + 1] = t; }
            float cs[KN]; cs[0] = mu[0];
            for (int k = 1; k < KN; ++k) cs[k] = cs[k - 1] + mu[k];
            int rho = 0; bool anyc = false;
            for (int k = 0; k < KN; ++k)
                if (mu[k] - (cs[k] - 1.0f) / (float)(k + 1) > 0.0f) { rho = k; anyc = true; }
            if (!anyc) rho = 0;
            float theta = (cs[rho] - 1.0f) / (float)(rho + 1);
            float ssum = 0;
            for (int k = 0; k < KN; ++k) { proj[k] = fmaxf(v[k] - theta, 0.0f); ssum += proj[k]; }
            float invs = 1.0f / (ssum + 1e-12f);
            for (int k = 0; k < KN; ++k) proj[k] *= invs;
            float nd = 0;
            for (int k = 0; k < KN; ++k) { float dd = proj[k] - b[k]; nd += dd * dd; }
            for (int k = 0; k < KN; ++k) b[k] = proj[k];
            if (nd < 1e-12f) break;   // ||proj-b|| < 1e-6
        }
        for (int k = 0; k < KN; ++k) beta_out[k] = proj[k];
    }
}

// ---------------------------------------------------------------- k_hist
// radix select over float bit patterns (all D >= 0 so uint order == float order)
template<int LEVEL>
__global__ __launch_bounds__(256) void k_hist(const float* __restrict__ D,
                                              const unsigned* __restrict__ sel,
                                              unsigned* __restrict__ gA,
                                              unsigned* __restrict__ gB)
{
    constexpr int NB = (LEVEL == 2) ? 4096 : 1024;
    __shared__ unsigned lha[NB];
    __shared__ unsigned lhb[(LEVEL == 0) ? 1 : NB];
    for (int i = threadIdx.x; i < NB; i += 256) lha[i] = 0;
    if constexpr (LEVEL != 0)
        for (int i = threadIdx.x; i < NB; i += 256) lhb[i] = 0;
    unsigned pA = 0, pB = 0;
    if constexpr (LEVEL != 0) { pA = sel[0]; pB = sel[2]; }
    __syncthreads();

    size_t stride = (size_t)gridDim.x * blockDim.x;
    for (size_t idx = (size_t)blockIdx.x * blockDim.x + threadIdx.x;
         idx < (size_t)NT * NT; idx += stride) {
        int i = (int)(idx >> 12), j = (int)(idx & 4095);
        bool valid = (i != j);
        unsigned key = valid ? __float_as_uint(D[idx]) : 0u;
        if constexpr (LEVEL == 0) {
            // values cluster into few exponent bins -> wave-aggregate
            unsigned bin = key >> 22;
            unsigned long long rem = __ballot(valid);
            while (rem) {
                int leader = __ffsll(rem) - 1;
                unsigned lbin = __shfl(bin, leader);
                unsigned long long match = __ballot(valid && (bin == lbin)) & rem;
                if ((threadIdx.x & 63) == leader)
                    atomicAdd(&lha[lbin], (unsigned)__popcll(match));
                rem &= ~match;
            }
        } else if constexpr (LEVEL == 1) {
            if (valid) {
                if ((key >> 22) == pA) atomicAdd(&lha[(key >> 12) & 1023], 1u);
                if ((key >> 22) == pB) atomicAdd(&lhb[(key >> 12) & 1023], 1u);
            }
        } else {
            if (valid) {
                if ((key >> 12) == pA) atomicAdd(&lha[key & 4095], 1u);
                if ((key >> 12) == pB) atomicAdd(&lhb[key & 4095], 1u);
            }
        }
    }
    __syncthreads();
    for (int i2 = threadIdx.x; i2 < NB; i2 += 256) {
        unsigned c = lha[i2];
        if (c) atomicAdd(&gA[i2], c);
        if constexpr (LEVEL != 0) {
            unsigned cb = lhb[i2];
            if (cb) atomicAdd(&gB[i2], cb);
        }
    }
}

// ---------------------------------------------------------------- k_scan
template<int LEVEL>
__global__ __launch_bounds__(64) void k_scan(const unsigned* __restrict__ hA,
                                             const unsigned* __restrict__ hB,
                                             unsigned* __restrict__ sel,
                                             float* __restrict__ params)
{
    constexpr int NB = (LEVEL == 2) ? 4096 : 1024;
    constexpr int C = NB / 64;
    int lane = threadIdx.x;
    for (int t = 0; t < 2; ++t) {
        const unsigned* h = (LEVEL == 0) ? hA : (t == 0 ? hA : hB);
        unsigned r = sel[t * 2 + 1];
        unsigned s = 0;
        for (int i = 0; i < C; ++i) s += h[lane * C + i];
        unsigned x = s;
        #pragma unroll
        for (int off = 1; off < 64; off <<= 1) {
            unsigned y = __shfl_up(x, off);
            if (lane >= off) x += y;
        }
        unsigned base = x - s;
        bool has = (r >= base) && (r < base + s);
        unsigned long long mm = __ballot(has);
        int leader = __ffsll(mm) - 1;
        unsigned bin = 0, cb = 0;
        if (lane == leader) {
            unsigned cc = base;
            for (int i = 0; i < C; ++i) {
                unsigned hv = h[lane * C + i];
                if (r < cc + hv) { bin = lane * C + i; cb = cc; break; }
                cc += hv;
            }
        }
        bin = __shfl(bin, leader);
        cb = __shfl(cb, leader);
        if (lane == 0) {
            if (LEVEL == 0)      sel[t * 2 + 0] = bin;
            else if (LEVEL == 1) sel[t * 2 + 0] = (sel[t * 2 + 0] << 10) | bin;
            else                 sel[4 + t]     = (sel[t * 2 + 0] << 12) | bin;
            sel[t * 2 + 1] = r - cb;
        }
    }
    if (LEVEL == 2 && lane == 0) {
        float vA = __uint_as_float(sel[4]);
        float vB = __uint_as_float(sel[5]);
        float med = 0.5f * (vA + vB);
        float bw = (med + 1e-6f) * 0.25f;
        #pragma unroll
        for (int k = 0; k < KN; ++k) params[k] = 1.0f / (bw * (float)(1 << k));
    }
}

// ---------------------------------------------------------------- k_wsum
__global__ __launch_bounds__(256) void k_wsum(const float* __restrict__ D,
                                              const float* __restrict__ params,
                                              const float* __restrict__ beta,
                                              double* __restrict__ partials)
{
    float i0 = params[0], i1 = params[1], i2 = params[2], i3 = params[3], i4 = params[4];
    float b0 = beta[0], b1 = beta[1], b2 = beta[2], b3 = beta[3], b4 = beta[4];
    const double wDiag = 1.0 / ((double)NS * (NS - 1));
    const double wOff = -1.0 / ((double)NS * NS);
    double acc = 0.0;
    size_t stride = (size_t)gridDim.x * blockDim.x;
    for (size_t idx = (size_t)blockIdx.x * blockDim.x + threadIdx.x;
         idx < (size_t)NT * NT; idx += stride) {
        int i = (int)(idx >> 12), j = (int)(idx & 4095);
        if (i == j) continue;
        float sq = D[idx];
        float v = b0 * expf(-sq * i0) + b1 * expf(-sq * i1) + b2 * expf(-sq * i2)
                + b3 * expf(-sq * i3) + b4 * expf(-sq * i4);
        bool same = (i < NS) == (j < NS);
        acc += (same ? wDiag : wOff) * (double)v;
    }
    __shared__ double red[256];
    red[threadIdx.x] = acc;
    __syncthreads();
    for (int off = 128; off > 0; off >>= 1) {
        if (threadIdx.x < off) red[threadIdx.x] += red[threadIdx.x + off];
        __syncthreads();
    }
    if (threadIdx.x == 0) partials[blockIdx.x] = red[0];
}

// ---------------------------------------------------------------- k_final
__global__ __launch_bounds__(256) void k_final(const double* __restrict__ partials,
                                               float* __restrict__ out)
{
    double acc = 0;
    for (int i = threadIdx.x; i < 2048; i += 256) acc += partials[i];
    __shared__ double red[256];
    red[threadIdx.x] = acc;
    __syncthreads();
    for (int off = 128; off > 0; off >>= 1) {
        if (threadIdx.x < off) red[threadIdx.x] += red[threadIdx.x + off];
        __syncthreads();
    }
    if (threadIdx.x == 0) out[0] = (float)fmax(red[0], 0.0);
}

// ---------------------------------------------------------------- launch
extern "C" void kernel_launch(void* const* d_in, const int* in_sizes, int n_in,
                              void* d_out, int out_size, void* d_ws, size_t ws_size,
                              hipStream_t stream)
{
    const float* S = (const float*)d_in[0];
    const float* T = (const float*)d_in[1];
    const float* beta = (const float*)d_in[2];
    float* out = (float*)d_out;

    // ws layout (requires ~64.1 MiB)
    float* D = (float*)d_ws;                       // 16777216 f
    float* norms = D + (size_t)NT * NT;            // 4096 f
    float* g = norms + NT;                         // 5120 f
    float* beta2 = g + 1024 * KN;                  // 8 f
    float* params = beta2 + 8;                     // 16 f
    unsigned* sel = (unsigned*)(params + 16);      // 16 u
    unsigned* hists = sel + 16;                    // 11264 u
    unsigned* hL0 = hists;                         // 1024
    unsigned* hL1A = hL0 + 1024;                   // 1024
    unsigned* hL1B = hL1A + 1024;                  // 1024
    unsigned* hL2A = hL1B + 1024;                  // 4096
    unsigned* hL2B = hL2A + 4096;                  // 4096
    double* partials = (double*)(hists + 11264);   // 2048 d

    k_init<<<dim3(1), dim3(256), 0, stream>>>(hists, sel);
    k_norms<<<dim3(NT), dim3(64), 0, stream>>>(S, T, norms);
    k_dist<<<dim3(64, 64), dim3(256), 0, stream>>>(S, T, norms, D);
    k_gmat<<<dim3(1024), dim3(64), 0, stream>>>(S, T, g);
    k_beta<<<dim3(1), dim3(64), 0, stream>>>(g, beta, beta2);
    k_hist<0><<<dim3(2048), dim3(256), 0, stream>>>(D, sel, hL0, hL0);
    k_scan<0><<<dim3(1), dim3(64), 0, stream>>>(hL0, hL0, sel, params);
    k_hist<1><<<dim3(2048), dim3(256), 0, stream>>>(D, sel, hL1A, hL1B);
    k_scan<1><<<dim3(1), dim3(64), 0, stream>>>(hL1A, hL1B, sel, params);
    k_hist<2><<<dim3(2048), dim3(256), 0, stream>>>(D, sel, hL2A, hL2B);
    k_scan<2><<<dim3(1), dim3(64), 0, stream>>>(hL2A, hL2B, sel, params);
    k_wsum<<<dim3(2048), dim3(256), 0, stream>>>(D, params, beta2, partials);
    k_final<<<dim3(1), dim3(256), 0, stream>>>(partials, out);
}

// Round 2
// 267.918 us; speedup vs baseline: 1.9774x; 1.9774x over previous
//
#include <hip/hip_runtime.h>
#include <math.h>

#define NT 4096
#define NS 2048
#define DDIM 512
#define KN 5
#define NTILES 528   // 32*33/2 triangle tiles of 128x128

typedef __bf16 bf16x8 __attribute__((ext_vector_type(8)));
typedef float f32x4 __attribute__((ext_vector_type(4)));
typedef unsigned short u16x8 __attribute__((ext_vector_type(8)));

static __device__ inline unsigned short f2bf(float x) {
    unsigned u = __float_as_uint(x);
    unsigned r = (u + 0x7fffu + ((u >> 16) & 1u)) >> 16;
    return (unsigned short)r;
}
static __device__ inline float bf2f(unsigned short h) {
    return __uint_as_float(((unsigned)h) << 16);
}

static __device__ inline void tri_map(int b, int& bx, int& by) {
    int x = (int)((sqrtf(8.0f * (float)b + 1.0f) - 1.0f) * 0.5f);
    while ((x + 1) * (x + 2) / 2 <= b) ++x;
    while (x * (x + 1) / 2 > b) --x;
    bx = x;
    by = b - x * (x + 1) / 2;
}

// ---------------------------------------------------------------- k_prep
// split fp32 -> bf16 hi/lo planes, row norms, zero hists, init sel
__global__ __launch_bounds__(64) void k_prep(const float* __restrict__ S,
                                             const float* __restrict__ T,
                                             unsigned short* __restrict__ Hi,
                                             unsigned short* __restrict__ Lo,
                                             float* __restrict__ norms,
                                             unsigned* __restrict__ hists,
                                             unsigned* __restrict__ sel)
{
    int r = blockIdx.x, l = threadIdx.x;
    if (r < 176) hists[r * 64 + l] = 0;          // 176*64 = 11264
    if (r == 300 && l == 0) {
        sel[0] = 0u; sel[1] = 8386559u;          // middle ranks of 4096*4095
        sel[2] = 0u; sel[3] = 8386560u;
    }
    const float* row = (r < NS) ? S + (size_t)r * DDIM : T + (size_t)(r - NS) * DDIM;
    float4 v1 = *(const float4*)(row + l * 8);
    float4 v2 = *(const float4*)(row + l * 8 + 4);
    float s = v1.x*v1.x + v1.y*v1.y + v1.z*v1.z + v1.w*v1.w
            + v2.x*v2.x + v2.y*v2.y + v2.z*v2.z + v2.w*v2.w;
    #pragma unroll
    for (int m = 32; m > 0; m >>= 1) s += __shfl_xor(s, m);
    if (l == 0) norms[r] = s;

    float xs[8] = { v1.x, v1.y, v1.z, v1.w, v2.x, v2.y, v2.z, v2.w };
    u16x8 hv, lv;
    #pragma unroll
    for (int k = 0; k < 8; ++k) {
        unsigned short h = f2bf(xs[k]);
        hv[k] = h;
        lv[k] = f2bf(xs[k] - bf2f(h));
    }
    *(u16x8*)&Hi[(size_t)r * DDIM + l * 8] = hv;
    *(u16x8*)&Lo[(size_t)r * DDIM + l * 8] = lv;
}

// ---------------------------------------------------------------- k_dist_mfma
// upper-triangle 128x128 tiles of D = max(n_i+n_j-2*dot,0) via split-bf16 MFMA,
// with fused level-0 radix histogram (key>>22) on the fly.
__global__ __launch_bounds__(256) void k_dist_mfma(const unsigned short* __restrict__ Hi,
                                                   const unsigned short* __restrict__ Lo,
                                                   const float* __restrict__ norms,
                                                   float* __restrict__ D,
                                                   unsigned* __restrict__ gHist)
{
    __shared__ __align__(16) unsigned short sHi[2][128][32];  // [0]=A rows, [1]=B rows
    __shared__ __align__(16) unsigned short sLo[2][128][32];
    __shared__ unsigned histL[1024];

    int bx, by;
    tri_map(blockIdx.x, bx, by);
    const int m0 = by * 128, n0 = bx * 128;      // by <= bx : rows m0, cols n0

    for (int i = threadIdx.x; i < 1024; i += 256) histL[i] = 0;

    const int tid = threadIdx.x;
    const int w = tid >> 6, l = tid & 63;
    const int wr = w >> 1, wc = w & 1;
    const int q = l >> 4;

    // staging coordinates (pre-swizzled source slot so LDS stays linear)
    const int srow = w * 16 + (l >> 2);              // 0..63 within half-tile
    const int sslot = (l & 3) ^ (srow & 3);
    const size_t gA0 = (size_t)(m0 + srow) * DDIM + sslot * 8;
    const size_t gA1 = (size_t)(m0 + srow + 64) * DDIM + sslot * 8;
    const size_t gB0 = (size_t)(n0 + srow) * DDIM + sslot * 8;
    const size_t gB1 = (size_t)(n0 + srow + 64) * DDIM + sslot * 8;
    const unsigned ldsOff = w * 1024;

    f32x4 acc[4][4] = {};
    const int ra_base = wr * 64 + (l & 15);
    const int rb_base = wc * 64 + (l & 15);

    for (int k0 = 0; k0 < DDIM; k0 += 32) {
        __syncthreads();
#define GLD(dstbase, srcptr, goff)                                                        \
        __builtin_amdgcn_global_load_lds(                                                 \
            (const __attribute__((address_space(1))) unsigned*)((srcptr) + (goff) + k0),  \
            (__attribute__((address_space(3))) unsigned*)((char*)(dstbase) + ldsOff),     \
            16, 0, 0)
        GLD(&sHi[0][0][0],  Hi, gA0);
        GLD(&sHi[0][64][0], Hi, gA1);
        GLD(&sLo[0][0][0],  Lo, gA0);
        GLD(&sLo[0][64][0], Lo, gA1);
        GLD(&sHi[1][0][0],  Hi, gB0);
        GLD(&sHi[1][64][0], Hi, gB1);
        GLD(&sLo[1][0][0],  Lo, gB0);
        GLD(&sLo[1][64][0], Lo, gB1);
#undef GLD
        __syncthreads();

        bf16x8 ah[4], al[4], bh[4], bl[4];
        #pragma unroll
        for (int m = 0; m < 4; ++m) {
            int ra = ra_base + m * 16;
            unsigned off = ra * 64 + ((q ^ (ra & 3)) << 4);
            ah[m] = *(const bf16x8*)((const char*)&sHi[0][0][0] + off);
            al[m] = *(const bf16x8*)((const char*)&sLo[0][0][0] + off);
        }
        #pragma unroll
        for (int n = 0; n < 4; ++n) {
            int rb = rb_base + n * 16;
            unsigned off = rb * 64 + ((q ^ (rb & 3)) << 4);
            bh[n] = *(const bf16x8*)((const char*)&sHi[1][0][0] + off);
            bl[n] = *(const bf16x8*)((const char*)&sLo[1][0][0] + off);
        }
        #pragma unroll
        for (int m = 0; m < 4; ++m)
            #pragma unroll
            for (int n = 0; n < 4; ++n) {
                acc[m][n] = __builtin_amdgcn_mfma_f32_16x16x32_bf16(ah[m], bh[n], acc[m][n], 0, 0, 0);
                acc[m][n] = __builtin_amdgcn_mfma_f32_16x16x32_bf16(ah[m], bl[n], acc[m][n], 0, 0, 0);
                acc[m][n] = __builtin_amdgcn_mfma_f32_16x16x32_bf16(al[m], bh[n], acc[m][n], 0, 0, 0);
            }
    }

    // epilogue: D values + fused level-0 histogram (wave-aggregated)
    const unsigned weight = (bx != by) ? 2u : 1u;
    const int colBase = n0 + wc * 64 + (l & 15);
    const int rowBase = m0 + wr * 64 + (q << 2);
    #pragma unroll
    for (int m = 0; m < 4; ++m) {
        #pragma unroll
        for (int n = 0; n < 4; ++n) {
            int col = colBase + n * 16;
            float nc = norms[col];
            #pragma unroll
            for (int j = 0; j < 4; ++j) {
                int row = rowBase + m * 16 + j;
                float d = fmaxf(norms[row] + nc - 2.0f * acc[m][n][j], 0.0f);
                D[(size_t)row * NT + col] = d;
                bool valid = (row != col);
                unsigned bin = __float_as_uint(d) >> 22;
                unsigned long long rem = __ballot(valid);
                while (rem) {
                    int leader = __ffsll((unsigned long long)rem) - 1;
                    unsigned lbin = __shfl(bin, leader);
                    unsigned long long match = __ballot(valid && (bin == lbin)) & rem;
                    if (l == leader) atomicAdd(&histL[lbin], (unsigned)__popcll(match) * weight);
                    rem &= ~match;
                }
            }
        }
    }
    __syncthreads();
    for (int i = threadIdx.x; i < 1024; i += 256) {
        unsigned c = histL[i];
        if (c) atomicAdd(&gHist[i], c);
    }
}

// ---------------------------------------------------------------- k_gmat
__global__ __launch_bounds__(64) void k_gmat(const float* __restrict__ S,
                                             const float* __restrict__ T,
                                             float* __restrict__ g)
{
    int p = blockIdx.x;
    int lane = threadIdx.x;
    const float* a = S + (size_t)(2 * p) * DDIM;
    const float* b = S + (size_t)(2 * p + 1) * DDIM;
    const float* c = T + (size_t)(2 * p) * DDIM;
    const float* d = T + (size_t)(2 * p + 1) * DDIM;
    float s01 = 0, s23 = 0, s02 = 0, s13 = 0, s03 = 0, s12 = 0;
    for (int k = lane; k < DDIM; k += 64) {
        float va = a[k], vb = b[k], vc = c[k], vd = d[k];
        float t01 = va - vb, t23 = vc - vd, t02 = va - vc, t13 = vb - vd, t03 = va - vd, t12 = vb - vc;
        s01 += t01*t01; s23 += t23*t23; s02 += t02*t02;
        s13 += t13*t13; s03 += t03*t03; s12 += t12*t12;
    }
    #pragma unroll
    for (int m = 32; m > 0; m >>= 1) {
        s01 += __shfl_xor(s01, m); s23 += __shfl_xor(s23, m);
        s02 += __shfl_xor(s02, m); s13 += __shfl_xor(s13, m);
        s03 += __shfl_xor(s03, m); s12 += __shfl_xor(s12, m);
    }
    if (lane == 0) {
        float v[6] = { s01, s02, s03, s12, s13, s23 };
        for (int i = 0; i < 5; ++i)
            for (int j = 0; j < 5 - i; ++j)
                if (v[j] > v[j + 1]) { float t = v[j]; v[j] = v[j + 1]; v[j + 1] = t; }
        float med = 0.5f * (v[2] + v[3]);
        float bw = (med + 1e-6f) * 0.25f;
        #pragma unroll
        for (int k = 0; k < KN; ++k) {
            float inv = 1.0f / (bw * (float)(1 << k));
            g[(size_t)p * KN + k] = expf(-s01 * inv) + expf(-s23 * inv)
                                  - expf(-s02 * inv) - expf(-s13 * inv);
        }
    }
}

// ---------------------------------------------------------------- k_beta
__global__ __launch_bounds__(64) void k_beta(const float* __restrict__ g,
                                             const float* __restrict__ beta_in,
                                             float* __restrict__ beta_out)
{
    int lane = threadIdx.x;
    float gs[KN] = {0, 0, 0, 0, 0};
    float gg[15];
    #pragma unroll
    for (int i = 0; i < 15; ++i) gg[i] = 0.0f;
    for (int p = lane; p < 1024; p += 64) {
        float gv[KN];
        #pragma unroll
        for (int k = 0; k < KN; ++k) gv[k] = g[(size_t)p * KN + k];
        int idx = 0;
        #pragma unroll
        for (int a2 = 0; a2 < KN; ++a2) {
            gs[a2] += gv[a2];
            #pragma unroll
            for (int b2 = a2; b2 < KN; ++b2) gg[idx++] += gv[a2] * gv[b2];
        }
    }
    #pragma unroll
    for (int m = 32; m > 0; m >>= 1) {
        #pragma unroll
        for (int k = 0; k < KN; ++k) gs[k] += __shfl_xor(gs[k], m);
        #pragma unroll
        for (int i = 0; i < 15; ++i) gg[i] += __shfl_xor(gg[i], m);
    }
    if (lane == 0) {
        float Q[KN][KN], gm[KN];
        #pragma unroll
        for (int k = 0; k < KN; ++k) gm[k] = gs[k] * (1.0f / 1024.0f);
        int idx = 0;
        for (int a2 = 0; a2 < KN; ++a2)
            for (int b2 = a2; b2 < KN; ++b2) {
                float qv = gg[idx++] * (1.0f / 1024.0f) - gm[a2] * gm[b2];
                Q[a2][b2] = qv; Q[b2][a2] = qv;
            }
        for (int k = 0; k < KN; ++k) Q[k][k] += 0.001f;

        float b[KN], proj[KN];
        for (int k = 0; k < KN; ++k) { b[k] = beta_in[k]; proj[k] = b[k]; }
        for (int it = 0; it < 100; ++it) {
            float v[KN];
            for (int a2 = 0; a2 < KN; ++a2) {
                float qb = 0;
                for (int b2 = 0; b2 < KN; ++b2) qb += Q[a2][b2] * b[b2];
                v[a2] = b[a2] - qb;
            }
            float mu[KN];
            for (int k = 0; k < KN; ++k) mu[k] = v[k];
            for (int i = 0; i < KN - 1; ++i)
                for (int j = 0; j < KN - 1 - i; ++j)
                    if (mu[j] < mu[j + 1]) { float t = mu[j]; mu[j] = mu[j + 1]; mu[j + 1] = t; }
            float cs[KN]; cs[0] = mu[0];
            for (int k = 1; k < KN; ++k) cs[k] = cs[k - 1] + mu[k];
            int rho = 0; bool anyc = false;
            for (int k = 0; k < KN; ++k)
                if (mu[k] - (cs[k] - 1.0f) / (float)(k + 1) > 0.0f) { rho = k; anyc = true; }
            if (!anyc) rho = 0;
            float theta = (cs[rho] - 1.0f) / (float)(rho + 1);
            float ssum = 0;
            for (int k = 0; k < KN; ++k) { proj[k] = fmaxf(v[k] - theta, 0.0f); ssum += proj[k]; }
            float invs = 1.0f / (ssum + 1e-12f);
            for (int k = 0; k < KN; ++k) proj[k] *= invs;
            float nd = 0;
            for (int k = 0; k < KN; ++k) { float dd = proj[k] - b[k]; nd += dd * dd; }
            for (int k = 0; k < KN; ++k) b[k] = proj[k];
            if (nd < 1e-12f) break;
        }
        for (int k = 0; k < KN; ++k) beta_out[k] = proj[k];
    }
}

// ---------------------------------------------------------------- k_hist_tri (levels 1,2)
template<int LEVEL>
__global__ __launch_bounds__(256) void k_hist_tri(const float* __restrict__ D,
                                                  const unsigned* __restrict__ sel,
                                                  unsigned* __restrict__ gA,
                                                  unsigned* __restrict__ gB)
{
    constexpr int NB = (LEVEL == 2) ? 4096 : 1024;
    __shared__ unsigned lha[NB];
    __shared__ unsigned lhb[NB];
    for (int i = threadIdx.x; i < NB; i += 256) { lha[i] = 0; lhb[i] = 0; }
    unsigned pA = sel[0], pB = sel[2];
    int bx, by;
    tri_map(blockIdx.x, bx, by);
    int m0 = by * 128, n0 = bx * 128;
    unsigned wt = (bx != by) ? 2u : 1u;
    __syncthreads();
    for (int e = threadIdx.x; e < 16384; e += 256) {
        int r = m0 + (e >> 7), c = n0 + (e & 127);
        if (r == c) continue;
        unsigned key = __float_as_uint(D[(size_t)r * NT + c]);
        if constexpr (LEVEL == 1) {
            if ((key >> 22) == pA) atomicAdd(&lha[(key >> 12) & 1023], wt);
            if ((key >> 22) == pB) atomicAdd(&lhb[(key >> 12) & 1023], wt);
        } else {
            if ((key >> 12) == pA) atomicAdd(&lha[key & 4095], wt);
            if ((key >> 12) == pB) atomicAdd(&lhb[key & 4095], wt);
        }
    }
    __syncthreads();
    for (int i = threadIdx.x; i < NB; i += 256) {
        unsigned ca = lha[i];
        if (ca) atomicAdd(&gA[i], ca);
        unsigned cb = lhb[i];
        if (cb) atomicAdd(&gB[i], cb);
    }
}

// ---------------------------------------------------------------- k_scan
template<int LEVEL>
__global__ __launch_bounds__(64) void k_scan(const unsigned* __restrict__ hA,
                                             const unsigned* __restrict__ hB,
                                             unsigned* __restrict__ sel,
                                             float* __restrict__ params)
{
    constexpr int NB = (LEVEL == 2) ? 4096 : 1024;
    constexpr int C = NB / 64;
    int lane = threadIdx.x;
    for (int t = 0; t < 2; ++t) {
        const unsigned* h = (LEVEL == 0) ? hA : (t == 0 ? hA : hB);
        unsigned r = sel[t * 2 + 1];
        unsigned s = 0;
        for (int i = 0; i < C; ++i) s += h[lane * C + i];
        unsigned x = s;
        #pragma unroll
        for (int off = 1; off < 64; off <<= 1) {
            unsigned y = __shfl_up(x, off);
            if (lane >= off) x += y;
        }
        unsigned base = x - s;
        bool has = (r >= base) && (r < base + s);
        unsigned long long mm = __ballot(has);
        int leader = __ffsll(mm) - 1;
        unsigned bin = 0, cb = 0;
        if (lane == leader) {
            unsigned cc = base;
            for (int i = 0; i < C; ++i) {
                unsigned hv = h[lane * C + i];
                if (r < cc + hv) { bin = lane * C + i; cb = cc; break; }
                cc += hv;
            }
        }
        bin = __shfl(bin, leader);
        cb = __shfl(cb, leader);
        if (lane == 0) {
            if (LEVEL == 0)      sel[t * 2 + 0] = bin;
            else if (LEVEL == 1) sel[t * 2 + 0] = (sel[t * 2 + 0] << 10) | bin;
            else                 sel[4 + t]     = (sel[t * 2 + 0] << 12) | bin;
            sel[t * 2 + 1] = r - cb;
        }
    }
    if (LEVEL == 2 && lane == 0) {
        float vA = __uint_as_float(sel[4]);
        float vB = __uint_as_float(sel[5]);
        float med = 0.5f * (vA + vB);
        float bw = (med + 1e-6f) * 0.25f;
        #pragma unroll
        for (int k = 0; k < KN; ++k) params[k] = 1.0f / (bw * (float)(1 << k));
    }
}

// ---------------------------------------------------------------- k_wsum_tri
__global__ __launch_bounds__(256) void k_wsum_tri(const float* __restrict__ D,
                                                  const float* __restrict__ params,
                                                  const float* __restrict__ beta,
                                                  double* __restrict__ partials)
{
    float i0 = params[0], i1 = params[1], i2 = params[2], i3 = params[3], i4 = params[4];
    float b0 = beta[0], b1 = beta[1], b2 = beta[2], b3 = beta[3], b4 = beta[4];
    const double wDiag = 1.0 / ((double)NS * (NS - 1));
    const double wOff = -1.0 / ((double)NS * NS);
    int bx, by;
    tri_map(blockIdx.x, bx, by);
    int m0 = by * 128, n0 = bx * 128;
    double wt = (bx != by) ? 2.0 : 1.0;
    double acc = 0.0;
    for (int e = threadIdx.x; e < 16384; e += 256) {
        int r = m0 + (e >> 7), c = n0 + (e & 127);
        if (r == c) continue;
        float sq = D[(size_t)r * NT + c];
        float v = b0 * expf(-sq * i0) + b1 * expf(-sq * i1) + b2 * expf(-sq * i2)
                + b3 * expf(-sq * i3) + b4 * expf(-sq * i4);
        bool same = (r < NS) == (c < NS);
        acc += (same ? wDiag : wOff) * (double)v;
    }
    acc *= wt;
    __shared__ double red[256];
    red[threadIdx.x] = acc;
    __syncthreads();
    for (int off = 128; off > 0; off >>= 1) {
        if (threadIdx.x < off) red[threadIdx.x] += red[threadIdx.x + off];
        __syncthreads();
    }
    if (threadIdx.x == 0) partials[blockIdx.x] = red[0];
}

// ---------------------------------------------------------------- k_final
__global__ __launch_bounds__(256) void k_final(const double* __restrict__ partials,
                                               float* __restrict__ out, int count)
{
    double acc = 0;
    for (int i = threadIdx.x; i < count; i += 256) acc += partials[i];
    __shared__ double red[256];
    red[threadIdx.x] = acc;
    __syncthreads();
    for (int off = 128; off > 0; off >>= 1) {
        if (threadIdx.x < off) red[threadIdx.x] += red[threadIdx.x + off];
        __syncthreads();
    }
    if (threadIdx.x == 0) out[0] = (float)fmax(red[0], 0.0);
}

// ================================================================ fallback path
// (round-1 fp32 pipeline, used only if ws_size is too small for Hi/Lo planes)

__global__ __launch_bounds__(256) void k_init(unsigned* __restrict__ hists,
                                              unsigned* __restrict__ sel)
{
    for (int i = threadIdx.x; i < 11264; i += 256) hists[i] = 0;
    if (threadIdx.x == 0) {
        sel[0] = 0u; sel[1] = 8386559u;
        sel[2] = 0u; sel[3] = 8386560u;
    }
}

__global__ __launch_bounds__(64) void k_norms(const float* __restrict__ S,
                                              const float* __restrict__ T,
                                              float* __restrict__ norms)
{
    int r = blockIdx.x;
    int lane = threadIdx.x;
    const float* row = (r < NS) ? S + (size_t)r * DDIM : T + (size_t)(r - NS) * DDIM;
    float4 v1 = *(const float4*)(row + lane * 8);
    float4 v2 = *(const float4*)(row + lane * 8 + 4);
    float s = v1.x*v1.x + v1.y*v1.y + v1.z*v1.z + v1.w*v1.w
            + v2.x*v2.x + v2.y*v2.y + v2.z*v2.z + v2.w*v2.w;
    #pragma unroll
    for (int m = 32; m > 0; m >>= 1) s += __shfl_xor(s, m);
    if (lane == 0) norms[r] = s;
}

__global__ __launch_bounds__(256) void k_dist(const float* __restrict__ S,
                                              const float* __restrict__ T,
                                              const float* __restrict__ norms,
                                              float* __restrict__ D)
{
    __shared__ __align__(16) float sA[16][68];
    __shared__ __align__(16) float sB[16][68];
    const int tid = threadIdx.x;
    const int tx = tid & 15, ty = tid >> 4;
    const int m0 = blockIdx.y * 64, n0 = blockIdx.x * 64;
    const int lrow = tid >> 2;
    const int lk = (tid & 3) * 4;
    const int ar = m0 + lrow, br = n0 + lrow;
    const float* arow = (ar < NS) ? S + (size_t)ar * DDIM : T + (size_t)(ar - NS) * DDIM;
    const float* brow = (br < NS) ? S + (size_t)br * DDIM : T + (size_t)(br - NS) * DDIM;
    float acc[4][4] = {};
    for (int k0 = 0; k0 < DDIM; k0 += 16) {
        float4 va = *(const float4*)(arow + k0 + lk);
        float4 vb = *(const float4*)(brow + k0 + lk);
        __syncthreads();
        sA[lk+0][lrow] = va.x; sA[lk+1][lrow] = va.y; sA[lk+2][lrow] = va.z; sA[lk+3][lrow] = va.w;
        sB[lk+0][lrow] = vb.x; sB[lk+1][lrow] = vb.y; sB[lk+2][lrow] = vb.z; sB[lk+3][lrow] = vb.w;
        __syncthreads();
        #pragma unroll
        for (int kk = 0; kk < 16; ++kk) {
            float4 a = *(const float4*)&sA[kk][ty * 4];
            float4 b = *(const float4*)&sB[kk][tx * 4];
            acc[0][0] += a.x*b.x; acc[0][1] += a.x*b.y; acc[0][2] += a.x*b.z; acc[0][3] += a.x*b.w;
            acc[1][0] += a.y*b.x; acc[1][1] += a.y*b.y; acc[1][2] += a.y*b.z; acc[1][3] += a.y*b.w;
            acc[2][0] += a.z*b.x; acc[2][1] += a.z*b.y; acc[2][2] += a.z*b.z; acc[2][3] += a.z*b.w;
            acc[3][0] += a.w*b.x; acc[3][1] += a.w*b.y; acc[3][2] += a.w*b.z; acc[3][3] += a.w*b.w;
        }
    }
    #pragma unroll
    for (int i = 0; i < 4; ++i) {
        int r = m0 + ty * 4 + i;
        float nr = norms[r];
        float4 o;
        o.x = fmaxf(nr + norms[n0 + tx*4 + 0] - 2.0f * acc[i][0], 0.0f);
        o.y = fmaxf(nr + norms[n0 + tx*4 + 1] - 2.0f * acc[i][1], 0.0f);
        o.z = fmaxf(nr + norms[n0 + tx*4 + 2] - 2.0f * acc[i][2], 0.0f);
        o.w = fmaxf(nr + norms[n0 + tx*4 + 3] - 2.0f * acc[i][3], 0.0f);
        *(float4*)&D[(size_t)r * NT + n0 + tx * 4] = o;
    }
}

template<int LEVEL>
__global__ __launch_bounds__(256) void k_hist(const float* __restrict__ D,
                                              const unsigned* __restrict__ sel,
                                              unsigned* __restrict__ gA,
                                              unsigned* __restrict__ gB)
{
    constexpr int NB = (LEVEL == 2) ? 4096 : 1024;
    __shared__ unsigned lha[NB];
    __shared__ unsigned lhb[(LEVEL == 0) ? 1 : NB];
    for (int i = threadIdx.x; i < NB; i += 256) lha[i] = 0;
    if constexpr (LEVEL != 0)
        for (int i = threadIdx.x; i < NB; i += 256) lhb[i] = 0;
    unsigned pA = 0, pB = 0;
    if constexpr (LEVEL != 0) { pA = sel[0]; pB = sel[2]; }
    __syncthreads();

    size_t stride = (size_t)gridDim.x * blockDim.x;
    for (size_t idx = (size_t)blockIdx.x * blockDim.x + threadIdx.x;
         idx < (size_t)NT * NT; idx += stride) {
        int i = (int)(idx >> 12), j = (int)(idx & 4095);
        bool valid = (i != j);
        unsigned key = valid ? __float_as_uint(D[idx]) : 0u;
        if constexpr (LEVEL == 0) {
            unsigned bin = key >> 22;
            unsigned long long rem = __ballot(valid);
            while (rem) {
                int leader = __ffsll(rem) - 1;
                unsigned lbin = __shfl(bin, leader);
                unsigned long long match = __ballot(valid && (bin == lbin)) & rem;
                if ((threadIdx.x & 63) == leader)
                    atomicAdd(&lha[lbin], (unsigned)__popcll(match));
                rem &= ~match;
            }
        } else if constexpr (LEVEL == 1) {
            if (valid) {
                if ((key >> 22) == pA) atomicAdd(&lha[(key >> 12) & 1023], 1u);
                if ((key >> 22) == pB) atomicAdd(&lhb[(key >> 12) & 1023], 1u);
            }
        } else {
            if (valid) {
                if ((key >> 12) == pA) atomicAdd(&lha[key & 4095], 1u);
                if ((key >> 12) == pB) atomicAdd(&lhb[key & 4095], 1u);
            }
        }
    }
    __syncthreads();
    for (int i2 = threadIdx.x; i2 < NB; i2 += 256) {
        unsigned c = lha[i2];
        if (c) atomicAdd(&gA[i2], c);
        if constexpr (LEVEL != 0) {
            unsigned cb = lhb[i2];
            if (cb) atomicAdd(&gB[i2], cb);
        }
    }
}

__global__ __launch_bounds__(256) void k_wsum(const float* __restrict__ D,
                                              const float* __restrict__ params,
                                              const float* __restrict__ beta,
                                              double* __restrict__ partials)
{
    float i0 = params[0], i1 = params[1], i2 = params[2], i3 = params[3], i4 = params[4];
    float b0 = beta[0], b1 = beta[1], b2 = beta[2], b3 = beta[3], b4 = beta[4];
    const double wDiag = 1.0 / ((double)NS * (NS - 1));
    const double wOff = -1.0 / ((double)NS * NS);
    double acc = 0.0;
    size_t stride = (size_t)gridDim.x * blockDim.x;
    for (size_t idx = (size_t)blockIdx.x * blockDim.x + threadIdx.x;
         idx < (size_t)NT * NT; idx += stride) {
        int i = (int)(idx >> 12), j = (int)(idx & 4095);
        if (i == j) continue;
        float sq = D[idx];
        float v = b0 * expf(-sq * i0) + b1 * expf(-sq * i1) + b2 * expf(-sq * i2)
                + b3 * expf(-sq * i3) + b4 * expf(-sq * i4);
        bool same = (i < NS) == (j < NS);
        acc += (same ? wDiag : wOff) * (double)v;
    }
    __shared__ double red[256];
    red[threadIdx.x] = acc;
    __syncthreads();
    for (int off = 128; off > 0; off >>= 1) {
        if (threadIdx.x < off) red[threadIdx.x] += red[threadIdx.x + off];
        __syncthreads();
    }
    if (threadIdx.x == 0) partials[blockIdx.x] = red[0];
}

// ---------------------------------------------------------------- launch
extern "C" void kernel_launch(void* const* d_in, const int* in_sizes, int n_in,
                              void* d_out, int out_size, void* d_ws, size_t ws_size,
                              hipStream_t stream)
{
    const float* S = (const float*)d_in[0];
    const float* T = (const float*)d_in[1];
    const float* beta = (const float*)d_in[2];
    float* out = (float*)d_out;

    const size_t NEED_NEW = (size_t)NT * NT * 4 + (size_t)NT * DDIM * 2 * 2 + 82048 + NTILES * 8;

    if (ws_size >= NEED_NEW) {
        float* D = (float*)d_ws;                              // 4096*4096 f
        unsigned short* Hi = (unsigned short*)(D + (size_t)NT * NT);
        unsigned short* Lo = Hi + (size_t)NT * DDIM;
        float* norms = (float*)(Lo + (size_t)NT * DDIM);      // 4096 f
        float* g = norms + NT;                                // 5120 f
        float* beta2 = g + 1024 * KN;                         // 8 f
        float* params = beta2 + 8;                            // 8 f
        unsigned* sel = (unsigned*)(params + 8);              // 16 u
        unsigned* hists = sel + 16;                           // 11264 u
        unsigned* hL0 = hists;
        unsigned* hL1A = hL0 + 1024;
        unsigned* hL1B = hL1A + 1024;
        unsigned* hL2A = hL1B + 1024;
        unsigned* hL2B = hL2A + 4096;
        double* partials = (double*)(hists + 11264);          // 528 d

        k_prep<<<dim3(NT), dim3(64), 0, stream>>>(S, T, Hi, Lo, norms, hists, sel);
        k_dist_mfma<<<dim3(NTILES), dim3(256), 0, stream>>>(Hi, Lo, norms, D, hL0);
        k_gmat<<<dim3(1024), dim3(64), 0, stream>>>(S, T, g);
        k_beta<<<dim3(1), dim3(64), 0, stream>>>(g, beta, beta2);
        k_scan<0><<<dim3(1), dim3(64), 0, stream>>>(hL0, hL0, sel, params);
        k_hist_tri<1><<<dim3(NTILES), dim3(256), 0, stream>>>(D, sel, hL1A, hL1B);
        k_scan<1><<<dim3(1), dim3(64), 0, stream>>>(hL1A, hL1B, sel, params);
        k_hist_tri<2><<<dim3(NTILES), dim3(256), 0, stream>>>(D, sel, hL2A, hL2B);
        k_scan<2><<<dim3(1), dim3(64), 0, stream>>>(hL2A, hL2B, sel, params);
        k_wsum_tri<<<dim3(NTILES), dim3(256), 0, stream>>>(D, params, beta2, partials);
        k_final<<<dim3(1), dim3(256), 0, stream>>>(partials, out, NTILES);
    } else {
        // round-1 fp32 fallback
        float* D = (float*)d_ws;
        float* norms = D + (size_t)NT * NT;
        float* g = norms + NT;
        float* beta2 = g + 1024 * KN;
        float* params = beta2 + 8;
        unsigned* sel = (unsigned*)(params + 16);
        unsigned* hists = sel + 16;
        unsigned* hL0 = hists;
        unsigned* hL1A = hL0 + 1024;
        unsigned* hL1B = hL1A + 1024;
        unsigned* hL2A = hL1B + 1024;
        unsigned* hL2B = hL2A + 4096;
        double* partials = (double*)(hists + 11264);

        k_init<<<dim3(1), dim3(256), 0, stream>>>(hists, sel);
        k_norms<<<dim3(NT), dim3(64), 0, stream>>>(S, T, norms);
        k_dist<<<dim3(64, 64), dim3(256), 0, stream>>>(S, T, norms, D);
        k_gmat<<<dim3(1024), dim3(64), 0, stream>>>(S, T, g);
        k_beta<<<dim3(1), dim3(64), 0, stream>>>(g, beta, beta2);
        k_hist<0><<<dim3(2048), dim3(256), 0, stream>>>(D, sel, hL0, hL0);
        k_scan<0><<<dim3(1), dim3(64), 0, stream>>>(hL0, hL0, sel, params);
        k_hist<1><<<dim3(2048), dim3(256), 0, stream>>>(D, sel, hL1A, hL1B);
        k_scan<1><<<dim3(1), dim3(64), 0, stream>>>(hL1A, hL1B, sel, params);
        k_hist<2><<<dim3(2048), dim3(256), 0, stream>>>(D, sel, hL2A, hL2B);
        k_scan<2><<<dim3(1), dim3(64), 0, stream>>>(hL2A, hL2B, sel, params);
        k_wsum<<<dim3(2048), dim3(256), 0, stream>>>(D, params, beta2, partials);
        k_final<<<dim3(1), dim3(256), 0, stream>>>(partials, out, 2048);
    }
}

// Round 3
// 209.636 us; speedup vs baseline: 2.5271x; 1.2780x over previous
//
#include <hip/hip_runtime.h>
#include <math.h>

#define NT 4096
#define NS 2048
#define DDIM 512
#define KN 5
#define NTILES 528   // 32*33/2 triangle tiles of 128x128

typedef __bf16 bf16x8 __attribute__((ext_vector_type(8)));
typedef float f32x4 __attribute__((ext_vector_type(4)));
typedef unsigned short u16x8 __attribute__((ext_vector_type(8)));

static __device__ inline unsigned short f2bf(float x) {
    unsigned u = __float_as_uint(x);
    unsigned r = (u + 0x7fffu + ((u >> 16) & 1u)) >> 16;
    return (unsigned short)r;
}
static __device__ inline float bf2f(unsigned short h) {
    return __uint_as_float(((unsigned)h) << 16);
}

static __device__ inline void tri_map(int b, int& bx, int& by) {
    int x = (int)((sqrtf(8.0f * (float)b + 1.0f) - 1.0f) * 0.5f);
    while ((x + 1) * (x + 2) / 2 <= b) ++x;
    while (x * (x + 1) / 2 > b) --x;
    bx = x;
    by = b - x * (x + 1) / 2;
}

// ---------------------------------------------------------------- k_prep2
// fused: bf16 hi/lo split + row norms + per-pair g matrix + hist/sel init.
// block p owns rows 2p,2p+1 of S and of T (covers all 4096 rows once).
__global__ __launch_bounds__(64) void k_prep2(const float* __restrict__ S,
                                              const float* __restrict__ T,
                                              unsigned short* __restrict__ Hi,
                                              unsigned short* __restrict__ Lo,
                                              float* __restrict__ norms,
                                              float* __restrict__ g,
                                              unsigned* __restrict__ hists,
                                              unsigned* __restrict__ sel)
{
    int p = blockIdx.x, l = threadIdx.x;
    if (p < 176) hists[p * 64 + l] = 0;          // 176*64 = 11264
    if (p == 300 && l == 0) {
        sel[0] = 0u; sel[1] = 8386559u;          // middle ranks of 4096*4095
        sel[2] = 0u; sel[3] = 8386560u;
    }
    const float* r0 = S + (size_t)(2 * p) * DDIM;
    const float* r1 = r0 + DDIM;
    const float* r2 = T + (size_t)(2 * p) * DDIM;
    const float* r3 = r2 + DDIM;
    float a[8], b[8], c[8], d[8];
    *(float4*)&a[0] = *(const float4*)(r0 + l * 8); *(float4*)&a[4] = *(const float4*)(r0 + l * 8 + 4);
    *(float4*)&b[0] = *(const float4*)(r1 + l * 8); *(float4*)&b[4] = *(const float4*)(r1 + l * 8 + 4);
    *(float4*)&c[0] = *(const float4*)(r2 + l * 8); *(float4*)&c[4] = *(const float4*)(r2 + l * 8 + 4);
    *(float4*)&d[0] = *(const float4*)(r3 + l * 8); *(float4*)&d[4] = *(const float4*)(r3 + l * 8 + 4);

    float n0 = 0, n1 = 0, n2 = 0, n3 = 0;
    float s01 = 0, s23 = 0, s02 = 0, s13 = 0, s03 = 0, s12 = 0;
    u16x8 h0, l0, h1, l1, h2, l2, h3, l3;
    #pragma unroll
    for (int k = 0; k < 8; ++k) {
        float va = a[k], vb = b[k], vc = c[k], vd = d[k];
        n0 += va * va; n1 += vb * vb; n2 += vc * vc; n3 += vd * vd;
        float t01 = va - vb, t23 = vc - vd, t02 = va - vc, t13 = vb - vd, t03 = va - vd, t12 = vb - vc;
        s01 += t01*t01; s23 += t23*t23; s02 += t02*t02;
        s13 += t13*t13; s03 += t03*t03; s12 += t12*t12;
        unsigned short hh;
        hh = f2bf(va); h0[k] = hh; l0[k] = f2bf(va - bf2f(hh));
        hh = f2bf(vb); h1[k] = hh; l1[k] = f2bf(vb - bf2f(hh));
        hh = f2bf(vc); h2[k] = hh; l2[k] = f2bf(vc - bf2f(hh));
        hh = f2bf(vd); h3[k] = hh; l3[k] = f2bf(vd - bf2f(hh));
    }
    size_t g0 = (size_t)(2 * p) * DDIM + l * 8;
    size_t g1 = g0 + DDIM;
    size_t g2 = (size_t)(NS + 2 * p) * DDIM + l * 8;
    size_t g3 = g2 + DDIM;
    *(u16x8*)&Hi[g0] = h0; *(u16x8*)&Lo[g0] = l0;
    *(u16x8*)&Hi[g1] = h1; *(u16x8*)&Lo[g1] = l1;
    *(u16x8*)&Hi[g2] = h2; *(u16x8*)&Lo[g2] = l2;
    *(u16x8*)&Hi[g3] = h3; *(u16x8*)&Lo[g3] = l3;

    #pragma unroll
    for (int m = 32; m > 0; m >>= 1) {
        n0 += __shfl_xor(n0, m); n1 += __shfl_xor(n1, m);
        n2 += __shfl_xor(n2, m); n3 += __shfl_xor(n3, m);
        s01 += __shfl_xor(s01, m); s23 += __shfl_xor(s23, m);
        s02 += __shfl_xor(s02, m); s13 += __shfl_xor(s13, m);
        s03 += __shfl_xor(s03, m); s12 += __shfl_xor(s12, m);
    }
    if (l == 0) {
        norms[2 * p] = n0; norms[2 * p + 1] = n1;
        norms[NS + 2 * p] = n2; norms[NS + 2 * p + 1] = n3;
        float v[6] = { s01, s02, s03, s12, s13, s23 };
        for (int i = 0; i < 5; ++i)
            for (int j = 0; j < 5 - i; ++j)
                if (v[j] > v[j + 1]) { float t = v[j]; v[j] = v[j + 1]; v[j + 1] = t; }
        float med = 0.5f * (v[2] + v[3]);
        float bw = (med + 1e-6f) * 0.25f;
        #pragma unroll
        for (int k = 0; k < KN; ++k) {
            float inv = 1.0f / (bw * (float)(1 << k));
            g[(size_t)p * KN + k] = expf(-s01 * inv) + expf(-s23 * inv)
                                  - expf(-s02 * inv) - expf(-s13 * inv);
        }
    }
}

// ---------------------------------------------------------------- k_dist_mfma
// upper-triangle 128x128 tiles of D via split-bf16 MFMA, double-buffered LDS
// with prefetch (stage next K-step before computing current), fused level-0
// radix histogram.
__global__ __launch_bounds__(256) void k_dist_mfma(const unsigned short* __restrict__ Hi,
                                                   const unsigned short* __restrict__ Lo,
                                                   const float* __restrict__ norms,
                                                   float* __restrict__ D,
                                                   unsigned* __restrict__ gHist)
{
    __shared__ __align__(16) unsigned short sA[2][2][128][32];  // [buf][plane][row][col]
    __shared__ __align__(16) unsigned short sB[2][2][128][32];
    __shared__ unsigned histL[1024];

    int bb = blockIdx.x;
    int swz = (bb & 7) * 66 + (bb >> 3);         // 528 = 8*66, bijective XCD swizzle
    int bx, by;
    tri_map(swz, bx, by);
    const int m0 = by * 128, n0 = bx * 128;

    for (int i = threadIdx.x; i < 1024; i += 256) histL[i] = 0;

    const int tid = threadIdx.x;
    const int w = tid >> 6, l = tid & 63;
    const int wr = w >> 1, wc = w & 1;

    // staging: lane covers row (w*16 + l/4), slot (l&3); swizzle f(r)=((r&3)+((r>>2)&3))&3
    const int fs = (((l >> 2) & 3) + ((l >> 4) & 3)) & 3;
    const int chunk = (l & 3) ^ fs;
    const size_t gA0 = (size_t)(m0 + w * 16 + (l >> 2)) * DDIM + chunk * 8;
    const size_t gA1 = gA0 + (size_t)64 * DDIM;
    const size_t gB0 = (size_t)(n0 + w * 16 + (l >> 2)) * DDIM + chunk * 8;
    const size_t gB1 = gB0 + (size_t)64 * DDIM;
    const unsigned w1024 = w * 1024;

#define GLD(dst, srcptr, goff)                                                      \
    __builtin_amdgcn_global_load_lds(                                               \
        (const __attribute__((address_space(1))) unsigned*)((srcptr) + (goff)),     \
        (__attribute__((address_space(3))) unsigned*)((char*)(dst) + w1024), 16, 0, 0)
#define STAGE(buf, kk)                                  \
    do {                                                \
        GLD(&sA[buf][0][0][0],  Hi, gA0 + (kk));        \
        GLD(&sA[buf][0][64][0], Hi, gA1 + (kk));        \
        GLD(&sA[buf][1][0][0],  Lo, gA0 + (kk));        \
        GLD(&sA[buf][1][64][0], Lo, gA1 + (kk));        \
        GLD(&sB[buf][0][0][0],  Hi, gB0 + (kk));        \
        GLD(&sB[buf][0][64][0], Hi, gB1 + (kk));        \
        GLD(&sB[buf][1][0][0],  Lo, gB0 + (kk));        \
        GLD(&sB[buf][1][64][0], Lo, gB1 + (kk));        \
    } while (0)

    f32x4 acc[4][4] = {};
    const int q = l >> 4;
    const int fr = ((l & 3) + ((l >> 2) & 3)) & 3;
    const unsigned soff = ((unsigned)(q ^ fr)) << 4;
    const unsigned rowbA = (wr * 64 + (l & 15)) * 64 + soff;
    const unsigned rowbB = (wc * 64 + (l & 15)) * 64 + soff;

    STAGE(0, 0);
    __syncthreads();

    #pragma unroll 2
    for (int t = 0; t < 16; ++t) {
        const int cur = t & 1;
        if (t < 15) STAGE(cur ^ 1, (t + 1) * 32);

        bf16x8 ah[4], al[4], bh[4], bl[4];
        #pragma unroll
        for (int m = 0; m < 4; ++m) {
            ah[m] = *(const bf16x8*)((const char*)&sA[cur][0][0][0] + rowbA + m * 1024);
            al[m] = *(const bf16x8*)((const char*)&sA[cur][1][0][0] + rowbA + m * 1024);
        }
        #pragma unroll
        for (int n = 0; n < 4; ++n) {
            bh[n] = *(const bf16x8*)((const char*)&sB[cur][0][0][0] + rowbB + n * 1024);
            bl[n] = *(const bf16x8*)((const char*)&sB[cur][1][0][0] + rowbB + n * 1024);
        }
        #pragma unroll
        for (int m = 0; m < 4; ++m)
            #pragma unroll
            for (int n = 0; n < 4; ++n) {
                acc[m][n] = __builtin_amdgcn_mfma_f32_16x16x32_bf16(ah[m], bh[n], acc[m][n], 0, 0, 0);
                acc[m][n] = __builtin_amdgcn_mfma_f32_16x16x32_bf16(ah[m], bl[n], acc[m][n], 0, 0, 0);
                acc[m][n] = __builtin_amdgcn_mfma_f32_16x16x32_bf16(al[m], bh[n], acc[m][n], 0, 0, 0);
            }
        __syncthreads();
    }
#undef STAGE
#undef GLD

    // epilogue: D values + fused level-0 histogram (wave-aggregated)
    const unsigned weight = (bx != by) ? 2u : 1u;
    const int colBase = n0 + wc * 64 + (l & 15);
    const int rowBase = m0 + wr * 64 + (q << 2);
    #pragma unroll
    for (int m = 0; m < 4; ++m) {
        #pragma unroll
        for (int n = 0; n < 4; ++n) {
            int col = colBase + n * 16;
            float nc = norms[col];
            #pragma unroll
            for (int j = 0; j < 4; ++j) {
                int row = rowBase + m * 16 + j;
                float dv = fmaxf(norms[row] + nc - 2.0f * acc[m][n][j], 0.0f);
                D[(size_t)row * NT + col] = dv;
                bool valid = (row != col);
                unsigned bin = __float_as_uint(dv) >> 22;
                unsigned long long rem = __ballot(valid);
                while (rem) {
                    int leader = __ffsll((unsigned long long)rem) - 1;
                    unsigned lbin = __shfl(bin, leader);
                    unsigned long long match = __ballot(valid && (bin == lbin)) & rem;
                    if (l == leader) atomicAdd(&histL[lbin], (unsigned)__popcll(match) * weight);
                    rem &= ~match;
                }
            }
        }
    }
    __syncthreads();
    for (int i = threadIdx.x; i < 1024; i += 256) {
        unsigned c = histL[i];
        if (c) atomicAdd(&gHist[i], c);
    }
}

// ---------------------------------------------------------------- k_scan0_beta
// fused: level-0 scan (both targets) + beta fixed-point iteration.
__global__ __launch_bounds__(64) void k_scan0_beta(const unsigned* __restrict__ hL0,
                                                   const float* __restrict__ g,
                                                   const float* __restrict__ beta_in,
                                                   unsigned* __restrict__ sel,
                                                   float* __restrict__ beta_out)
{
    int lane = threadIdx.x;
    // ---- scan level 0 (two targets, same histogram) ----
    for (int t = 0; t < 2; ++t) {
        unsigned r = sel[t * 2 + 1];
        unsigned s = 0;
        for (int i = 0; i < 16; ++i) s += hL0[lane * 16 + i];
        unsigned x = s;
        #pragma unroll
        for (int off = 1; off < 64; off <<= 1) {
            unsigned y = __shfl_up(x, off);
            if (lane >= off) x += y;
        }
        unsigned base = x - s;
        bool has = (r >= base) && (r < base + s);
        unsigned long long mm = __ballot(has);
        int leader = __ffsll(mm) - 1;
        unsigned bin = 0, cb = 0;
        if (lane == leader) {
            unsigned cc = base;
            for (int i = 0; i < 16; ++i) {
                unsigned hv = hL0[lane * 16 + i];
                if (r < cc + hv) { bin = lane * 16 + i; cb = cc; break; }
                cc += hv;
            }
        }
        bin = __shfl(bin, leader);
        cb = __shfl(cb, leader);
        if (lane == 0) {
            sel[t * 2 + 0] = bin;
            sel[t * 2 + 1] = r - cb;
        }
    }
    // ---- beta ----
    float gs[KN] = {0, 0, 0, 0, 0};
    float gg[15];
    #pragma unroll
    for (int i = 0; i < 15; ++i) gg[i] = 0.0f;
    for (int p = lane; p < 1024; p += 64) {
        float gv[KN];
        #pragma unroll
        for (int k = 0; k < KN; ++k) gv[k] = g[(size_t)p * KN + k];
        int idx = 0;
        #pragma unroll
        for (int a2 = 0; a2 < KN; ++a2) {
            gs[a2] += gv[a2];
            #pragma unroll
            for (int b2 = a2; b2 < KN; ++b2) gg[idx++] += gv[a2] * gv[b2];
        }
    }
    #pragma unroll
    for (int m = 32; m > 0; m >>= 1) {
        #pragma unroll
        for (int k = 0; k < KN; ++k) gs[k] += __shfl_xor(gs[k], m);
        #pragma unroll
        for (int i = 0; i < 15; ++i) gg[i] += __shfl_xor(gg[i], m);
    }
    if (lane == 0) {
        float Q[KN][KN], gm[KN];
        #pragma unroll
        for (int k = 0; k < KN; ++k) gm[k] = gs[k] * (1.0f / 1024.0f);
        int idx = 0;
        for (int a2 = 0; a2 < KN; ++a2)
            for (int b2 = a2; b2 < KN; ++b2) {
                float qv = gg[idx++] * (1.0f / 1024.0f) - gm[a2] * gm[b2];
                Q[a2][b2] = qv; Q[b2][a2] = qv;
            }
        for (int k = 0; k < KN; ++k) Q[k][k] += 0.001f;

        float b[KN], proj[KN];
        for (int k = 0; k < KN; ++k) { b[k] = beta_in[k]; proj[k] = b[k]; }
        for (int it = 0; it < 100; ++it) {
            float v[KN];
            for (int a2 = 0; a2 < KN; ++a2) {
                float qb = 0;
                for (int b2 = 0; b2 < KN; ++b2) qb += Q[a2][b2] * b[b2];
                v[a2] = b[a2] - qb;
            }
            float mu[KN];
            for (int k = 0; k < KN; ++k) mu[k] = v[k];
            for (int i = 0; i < KN - 1; ++i)
                for (int j = 0; j < KN - 1 - i; ++j)
                    if (mu[j] < mu[j + 1]) { float t = mu[j]; mu[j] = mu[j + 1]; mu[j + 1] = t; }
            float cs[KN]; cs[0] = mu[0];
            for (int k = 1; k < KN; ++k) cs[k] = cs[k - 1] + mu[k];
            int rho = 0; bool anyc = false;
            for (int k = 0; k < KN; ++k)
                if (mu[k] - (cs[k] - 1.0f) / (float)(k + 1) > 0.0f) { rho = k; anyc = true; }
            if (!anyc) rho = 0;
            float theta = (cs[rho] - 1.0f) / (float)(rho + 1);
            float ssum = 0;
            for (int k = 0; k < KN; ++k) { proj[k] = fmaxf(v[k] - theta, 0.0f); ssum += proj[k]; }
            float invs = 1.0f / (ssum + 1e-12f);
            for (int k = 0; k < KN; ++k) proj[k] *= invs;
            float nd = 0;
            for (int k = 0; k < KN; ++k) { float dd = proj[k] - b[k]; nd += dd * dd; }
            for (int k = 0; k < KN; ++k) b[k] = proj[k];
            if (nd < 1e-12f) break;
        }
        for (int k = 0; k < KN; ++k) beta_out[k] = proj[k];
    }
}

// ---------------------------------------------------------------- k_hist_tri (levels 1,2)
template<int LEVEL>
__global__ __launch_bounds__(256) void k_hist_tri(const float* __restrict__ D,
                                                  const unsigned* __restrict__ sel,
                                                  unsigned* __restrict__ gA,
                                                  unsigned* __restrict__ gB)
{
    constexpr int NB = (LEVEL == 2) ? 4096 : 1024;
    __shared__ unsigned lha[NB];
    __shared__ unsigned lhb[NB];
    for (int i = threadIdx.x; i < NB; i += 256) { lha[i] = 0; lhb[i] = 0; }
    unsigned pA = sel[0], pB = sel[2];
    int bx, by;
    tri_map(blockIdx.x, bx, by);
    int m0 = by * 128, n0 = bx * 128;
    unsigned wt = (bx != by) ? 2u : 1u;
    __syncthreads();
    for (int v = threadIdx.x; v < 4096; v += 256) {
        int r = m0 + (v >> 5);
        int c0 = n0 + (v & 31) * 4;
        float4 dv = *(const float4*)&D[(size_t)r * NT + c0];
        const float* dd = (const float*)&dv;
        #pragma unroll
        for (int j = 0; j < 4; ++j) {
            if (r == c0 + j) continue;
            unsigned key = __float_as_uint(dd[j]);
            if constexpr (LEVEL == 1) {
                if ((key >> 22) == pA) atomicAdd(&lha[(key >> 12) & 1023], wt);
                if ((key >> 22) == pB) atomicAdd(&lhb[(key >> 12) & 1023], wt);
            } else {
                if ((key >> 12) == pA) atomicAdd(&lha[key & 4095], wt);
                if ((key >> 12) == pB) atomicAdd(&lhb[key & 4095], wt);
            }
        }
    }
    __syncthreads();
    for (int i = threadIdx.x; i < NB; i += 256) {
        unsigned ca = lha[i];
        if (ca) atomicAdd(&gA[i], ca);
        unsigned cb = lhb[i];
        if (cb) atomicAdd(&gB[i], cb);
    }
}

// ---------------------------------------------------------------- k_scan (levels 1,2)
template<int LEVEL>
__global__ __launch_bounds__(64) void k_scan(const unsigned* __restrict__ hA,
                                             const unsigned* __restrict__ hB,
                                             unsigned* __restrict__ sel,
                                             float* __restrict__ params)
{
    constexpr int NB = (LEVEL == 2) ? 4096 : 1024;
    constexpr int C = NB / 64;
    int lane = threadIdx.x;
    for (int t = 0; t < 2; ++t) {
        const unsigned* h = (t == 0 ? hA : hB);
        unsigned r = sel[t * 2 + 1];
        unsigned s = 0;
        for (int i = 0; i < C; ++i) s += h[lane * C + i];
        unsigned x = s;
        #pragma unroll
        for (int off = 1; off < 64; off <<= 1) {
            unsigned y = __shfl_up(x, off);
            if (lane >= off) x += y;
        }
        unsigned base = x - s;
        bool has = (r >= base) && (r < base + s);
        unsigned long long mm = __ballot(has);
        int leader = __ffsll(mm) - 1;
        unsigned bin = 0, cb = 0;
        if (lane == leader) {
            unsigned cc = base;
            for (int i = 0; i < C; ++i) {
                unsigned hv = h[lane * C + i];
                if (r < cc + hv) { bin = lane * C + i; cb = cc; break; }
                cc += hv;
            }
        }
        bin = __shfl(bin, leader);
        cb = __shfl(cb, leader);
        if (lane == 0) {
            if (LEVEL == 1) sel[t * 2 + 0] = (sel[t * 2 + 0] << 10) | bin;
            else            sel[4 + t]     = (sel[t * 2 + 0] << 12) | bin;
            sel[t * 2 + 1] = r - cb;
        }
    }
    if (LEVEL == 2 && lane == 0) {
        float vA = __uint_as_float(sel[4]);
        float vB = __uint_as_float(sel[5]);
        float med = 0.5f * (vA + vB);
        float bw = (med + 1e-6f) * 0.25f;
        #pragma unroll
        for (int k = 0; k < KN; ++k) params[k] = 1.0f / (bw * (float)(1 << k));
    }
}

// ---------------------------------------------------------------- k_wsum_tri
__global__ __launch_bounds__(256) void k_wsum_tri(const float* __restrict__ D,
                                                  const float* __restrict__ params,
                                                  const float* __restrict__ beta,
                                                  double* __restrict__ partials)
{
    float i0 = params[0], i1 = params[1], i2 = params[2], i3 = params[3], i4 = params[4];
    float b0 = beta[0], b1 = beta[1], b2 = beta[2], b3 = beta[3], b4 = beta[4];
    const double wDiag = 1.0 / ((double)NS * (NS - 1));
    const double wOff = -1.0 / ((double)NS * NS);
    int bx, by;
    tri_map(blockIdx.x, bx, by);
    int m0 = by * 128, n0 = bx * 128;
    double wt = (bx != by) ? 2.0 : 1.0;
    double acc = 0.0;
    for (int v = threadIdx.x; v < 4096; v += 256) {
        int r = m0 + (v >> 5);
        int c0 = n0 + (v & 31) * 4;
        float4 dv = *(const float4*)&D[(size_t)r * NT + c0];
        const float* dd = (const float*)&dv;
        #pragma unroll
        for (int j = 0; j < 4; ++j) {
            int c = c0 + j;
            if (r == c) continue;
            float sq = dd[j];
            float val = b0 * __expf(-sq * i0) + b1 * __expf(-sq * i1) + b2 * __expf(-sq * i2)
                      + b3 * __expf(-sq * i3) + b4 * __expf(-sq * i4);
            bool same = (r < NS) == (c < NS);
            acc += (same ? wDiag : wOff) * (double)val;
        }
    }
    acc *= wt;
    __shared__ double red[256];
    red[threadIdx.x] = acc;
    __syncthreads();
    for (int off = 128; off > 0; off >>= 1) {
        if (threadIdx.x < off) red[threadIdx.x] += red[threadIdx.x + off];
        __syncthreads();
    }
    if (threadIdx.x == 0) partials[blockIdx.x] = red[0];
}

// ---------------------------------------------------------------- k_final
__global__ __launch_bounds__(256) void k_final(const double* __restrict__ partials,
                                               float* __restrict__ out, int count)
{
    double acc = 0;
    for (int i = threadIdx.x; i < count; i += 256) acc += partials[i];
    __shared__ double red[256];
    red[threadIdx.x] = acc;
    __syncthreads();
    for (int off = 128; off > 0; off >>= 1) {
        if (threadIdx.x < off) red[threadIdx.x] += red[threadIdx.x + off];
        __syncthreads();
    }
    if (threadIdx.x == 0) out[0] = (float)fmax(red[0], 0.0);
}

// ---------------------------------------------------------------- launch
extern "C" void kernel_launch(void* const* d_in, const int* in_sizes, int n_in,
                              void* d_out, int out_size, void* d_ws, size_t ws_size,
                              hipStream_t stream)
{
    const float* S = (const float*)d_in[0];
    const float* T = (const float*)d_in[1];
    const float* beta = (const float*)d_in[2];
    float* out = (float*)d_out;

    float* D = (float*)d_ws;                              // 4096*4096 f
    unsigned short* Hi = (unsigned short*)(D + (size_t)NT * NT);
    unsigned short* Lo = Hi + (size_t)NT * DDIM;
    float* norms = (float*)(Lo + (size_t)NT * DDIM);      // 4096 f
    float* g = norms + NT;                                // 5120 f
    float* beta2 = g + 1024 * KN;                         // 8 f
    float* params = beta2 + 8;                            // 8 f
    unsigned* sel = (unsigned*)(params + 8);              // 16 u
    unsigned* hists = sel + 16;                           // 11264 u
    unsigned* hL0 = hists;
    unsigned* hL1A = hL0 + 1024;
    unsigned* hL1B = hL1A + 1024;
    unsigned* hL2A = hL1B + 1024;
    unsigned* hL2B = hL2A + 4096;
    double* partials = (double*)(hists + 11264);          // 528 d

    k_prep2<<<dim3(1024), dim3(64), 0, stream>>>(S, T, Hi, Lo, norms, g, hists, sel);
    k_dist_mfma<<<dim3(NTILES), dim3(256), 0, stream>>>(Hi, Lo, norms, D, hL0);
    k_scan0_beta<<<dim3(1), dim3(64), 0, stream>>>(hL0, g, beta, sel, beta2);
    k_hist_tri<1><<<dim3(NTILES), dim3(256), 0, stream>>>(D, sel, hL1A, hL1B);
    k_scan<1><<<dim3(1), dim3(64), 0, stream>>>(hL1A, hL1B, sel, params);
    k_hist_tri<2><<<dim3(NTILES), dim3(256), 0, stream>>>(D, sel, hL2A, hL2B);
    k_scan<2><<<dim3(1), dim3(64), 0, stream>>>(hL2A, hL2B, sel, params);
    k_wsum_tri<<<dim3(NTILES), dim3(256), 0, stream>>>(D, params, beta2, partials);
    k_final<<<dim3(1), dim3(256), 0, stream>>>(partials, out, NTILES);
}

// Round 4
// 192.593 us; speedup vs baseline: 2.7507x; 1.0885x over previous
//
#include <hip/hip_runtime.h>
#include <math.h>

#define NT 4096
#define NS 2048
#define DDIM 512
#define KN 5
#define NTILES 528   // 32*33/2 triangle tiles of 128x128

typedef __bf16 bf16x8 __attribute__((ext_vector_type(8)));
typedef float f32x4 __attribute__((ext_vector_type(4)));
typedef unsigned short u16x8 __attribute__((ext_vector_type(8)));

static __device__ inline unsigned short f2bf(float x) {
    unsigned u = __float_as_uint(x);
    unsigned r = (u + 0x7fffu + ((u >> 16) & 1u)) >> 16;
    return (unsigned short)r;
}
static __device__ inline float bf2f(unsigned short h) {
    return __uint_as_float(((unsigned)h) << 16);
}

static __device__ inline void tri_map(int b, int& bx, int& by) {
    int x = (int)((sqrtf(8.0f * (float)b + 1.0f) - 1.0f) * 0.5f);
    while ((x + 1) * (x + 2) / 2 <= b) ++x;
    while (x * (x + 1) / 2 > b) --x;
    bx = x;
    by = b - x * (x + 1) / 2;
}

// ---------------------------------------------------------------- k_prep2
// fused: bf16 hi/lo split + row norms + per-pair g matrix + hist/sel init.
// 256 threads = 4 wave-groups; block handles pairs 4b..4b+3.
__global__ __launch_bounds__(256) void k_prep2(const float* __restrict__ S,
                                               const float* __restrict__ T,
                                               unsigned short* __restrict__ Hi,
                                               unsigned short* __restrict__ Lo,
                                               float* __restrict__ norms,
                                               float* __restrict__ g,
                                               unsigned* __restrict__ hists,
                                               unsigned* __restrict__ sel)
{
    if (blockIdx.x < 44) hists[blockIdx.x * 256 + threadIdx.x] = 0;  // 44*256=11264
    if (blockIdx.x == 50 && threadIdx.x == 0) {
        sel[0] = 0u; sel[1] = 8386559u;          // middle ranks of 4096*4095
        sel[2] = 0u; sel[3] = 8386560u;
    }
    int p = blockIdx.x * 4 + (threadIdx.x >> 6);
    int l = threadIdx.x & 63;
    const float* r0 = S + (size_t)(2 * p) * DDIM;
    const float* r1 = r0 + DDIM;
    const float* r2 = T + (size_t)(2 * p) * DDIM;
    const float* r3 = r2 + DDIM;
    float a[8], b[8], c[8], d[8];
    *(float4*)&a[0] = *(const float4*)(r0 + l * 8); *(float4*)&a[4] = *(const float4*)(r0 + l * 8 + 4);
    *(float4*)&b[0] = *(const float4*)(r1 + l * 8); *(float4*)&b[4] = *(const float4*)(r1 + l * 8 + 4);
    *(float4*)&c[0] = *(const float4*)(r2 + l * 8); *(float4*)&c[4] = *(const float4*)(r2 + l * 8 + 4);
    *(float4*)&d[0] = *(const float4*)(r3 + l * 8); *(float4*)&d[4] = *(const float4*)(r3 + l * 8 + 4);

    float n0 = 0, n1 = 0, n2 = 0, n3 = 0;
    float s01 = 0, s23 = 0, s02 = 0, s13 = 0, s03 = 0, s12 = 0;
    u16x8 h0, l0, h1, l1, h2, l2, h3, l3;
    #pragma unroll
    for (int k = 0; k < 8; ++k) {
        float va = a[k], vb = b[k], vc = c[k], vd = d[k];
        n0 += va * va; n1 += vb * vb; n2 += vc * vc; n3 += vd * vd;
        float t01 = va - vb, t23 = vc - vd, t02 = va - vc, t13 = vb - vd;
        s01 += t01*t01; s23 += t23*t23; s02 += t02*t02; s13 += t13*t13;
        float t03 = va - vd, t12 = vb - vc;
        s03 += t03*t03; s12 += t12*t12;
        unsigned short hh;
        hh = f2bf(va); h0[k] = hh; l0[k] = f2bf(va - bf2f(hh));
        hh = f2bf(vb); h1[k] = hh; l1[k] = f2bf(vb - bf2f(hh));
        hh = f2bf(vc); h2[k] = hh; l2[k] = f2bf(vc - bf2f(hh));
        hh = f2bf(vd); h3[k] = hh; l3[k] = f2bf(vd - bf2f(hh));
    }
    size_t g0 = (size_t)(2 * p) * DDIM + l * 8;
    size_t g1 = g0 + DDIM;
    size_t g2 = (size_t)(NS + 2 * p) * DDIM + l * 8;
    size_t g3 = g2 + DDIM;
    *(u16x8*)&Hi[g0] = h0; *(u16x8*)&Lo[g0] = l0;
    *(u16x8*)&Hi[g1] = h1; *(u16x8*)&Lo[g1] = l1;
    *(u16x8*)&Hi[g2] = h2; *(u16x8*)&Lo[g2] = l2;
    *(u16x8*)&Hi[g3] = h3; *(u16x8*)&Lo[g3] = l3;

    #pragma unroll
    for (int m = 32; m > 0; m >>= 1) {
        n0 += __shfl_xor(n0, m); n1 += __shfl_xor(n1, m);
        n2 += __shfl_xor(n2, m); n3 += __shfl_xor(n3, m);
        s01 += __shfl_xor(s01, m); s23 += __shfl_xor(s23, m);
        s02 += __shfl_xor(s02, m); s13 += __shfl_xor(s13, m);
        s03 += __shfl_xor(s03, m); s12 += __shfl_xor(s12, m);
    }
    if (l == 0) {
        norms[2 * p] = n0; norms[2 * p + 1] = n1;
        norms[NS + 2 * p] = n2; norms[NS + 2 * p + 1] = n3;
        float v[6] = { s01, s02, s03, s12, s13, s23 };
        for (int i = 0; i < 5; ++i)
            for (int j = 0; j < 5 - i; ++j)
                if (v[j] > v[j + 1]) { float t = v[j]; v[j] = v[j + 1]; v[j + 1] = t; }
        float med = 0.5f * (v[2] + v[3]);
        float bw = (med + 1e-6f) * 0.25f;
        #pragma unroll
        for (int k = 0; k < KN; ++k) {
            float inv = 1.0f / (bw * (float)(1 << k));
            g[(size_t)p * KN + k] = expf(-s01 * inv) + expf(-s23 * inv)
                                  - expf(-s02 * inv) - expf(-s13 * inv);
        }
    }
}

// ---------------------------------------------------------------- k_dist_mfma
// pure GEMM: upper-triangle 128x128 tiles of D via split-bf16 MFMA, dbuf LDS,
// operand-swapped MFMA so each lane holds 4 consecutive D columns, epilogue
// LDS-transposes each wave's 64x64 tile into full 256B-row float4 stores.
__global__ __launch_bounds__(256) void k_dist_mfma(const unsigned short* __restrict__ Hi,
                                                   const unsigned short* __restrict__ Lo,
                                                   const float* __restrict__ norms,
                                                   float* __restrict__ D)
{
    __shared__ __align__(16) unsigned short sA[2][2][128][32];  // [buf][plane][row][col]
    __shared__ __align__(16) unsigned short sB[2][2][128][32];

    int bb = blockIdx.x;
    int swz = (bb & 7) * 66 + (bb >> 3);         // 528 = 8*66, bijective XCD swizzle
    int bx, by;
    tri_map(swz, bx, by);
    const int m0 = by * 128, n0 = bx * 128;

    const int tid = threadIdx.x;
    const int w = tid >> 6, l = tid & 63;
    const int wr = w >> 1, wc = w & 1;

    // staging: lane covers row (w*16 + l/4), slot (l&3); swizzle f(r)=((r&3)+((r>>2)&3))&3
    const int chunk = (l & 3) ^ ((((l >> 2) & 3) + ((l >> 4) & 3)) & 3);
    const size_t gA0 = (size_t)(m0 + w * 16 + (l >> 2)) * DDIM + chunk * 8;
    const size_t gA1 = gA0 + (size_t)64 * DDIM;
    const size_t gB0 = (size_t)(n0 + w * 16 + (l >> 2)) * DDIM + chunk * 8;
    const size_t gB1 = gB0 + (size_t)64 * DDIM;
    const unsigned w1024 = w * 1024;

#define GLD(dst, srcptr, goff)                                                      \
    __builtin_amdgcn_global_load_lds(                                               \
        (const __attribute__((address_space(1))) unsigned*)((srcptr) + (goff)),     \
        (__attribute__((address_space(3))) unsigned*)((char*)(dst) + w1024), 16, 0, 0)
#define STAGE(buf, kk)                                  \
    do {                                                \
        GLD(&sA[buf][0][0][0],  Hi, gA0 + (kk));        \
        GLD(&sA[buf][0][64][0], Hi, gA1 + (kk));        \
        GLD(&sA[buf][1][0][0],  Lo, gA0 + (kk));        \
        GLD(&sA[buf][1][64][0], Lo, gA1 + (kk));        \
        GLD(&sB[buf][0][0][0],  Hi, gB0 + (kk));        \
        GLD(&sB[buf][0][64][0], Hi, gB1 + (kk));        \
        GLD(&sB[buf][1][0][0],  Lo, gB0 + (kk));        \
        GLD(&sB[buf][1][64][0], Lo, gB1 + (kk));        \
    } while (0)

    f32x4 acc[4][4] = {};
    const int q = l >> 4;
    const int fr = ((l & 3) + ((l >> 2) & 3)) & 3;
    const unsigned soff = ((unsigned)(q ^ fr)) << 4;
    const unsigned rowbA = (wr * 64 + (l & 15)) * 64 + soff;
    const unsigned rowbB = (wc * 64 + (l & 15)) * 64 + soff;

    STAGE(0, 0);
    __syncthreads();

    #pragma unroll 2
    for (int t = 0; t < 16; ++t) {
        const int cur = t & 1;
        if (t < 15) STAGE(cur ^ 1, (t + 1) * 32);

        bf16x8 ah[4], al[4], bh[4], bl[4];
        #pragma unroll
        for (int m = 0; m < 4; ++m) {
            ah[m] = *(const bf16x8*)((const char*)&sA[cur][0][0][0] + rowbA + m * 1024);
            al[m] = *(const bf16x8*)((const char*)&sA[cur][1][0][0] + rowbA + m * 1024);
        }
        #pragma unroll
        for (int n = 0; n < 4; ++n) {
            bh[n] = *(const bf16x8*)((const char*)&sB[cur][0][0][0] + rowbB + n * 1024);
            bl[n] = *(const bf16x8*)((const char*)&sB[cur][1][0][0] + rowbB + n * 1024);
        }
        // operand-swapped: first operand = B rows -> acc reg indexes D columns
        #pragma unroll
        for (int m = 0; m < 4; ++m)
            #pragma unroll
            for (int n = 0; n < 4; ++n) {
                acc[m][n] = __builtin_amdgcn_mfma_f32_16x16x32_bf16(bh[n], ah[m], acc[m][n], 0, 0, 0);
                acc[m][n] = __builtin_amdgcn_mfma_f32_16x16x32_bf16(bl[n], ah[m], acc[m][n], 0, 0, 0);
                acc[m][n] = __builtin_amdgcn_mfma_f32_16x16x32_bf16(bh[n], al[m], acc[m][n], 0, 0, 0);
            }
        __syncthreads();
    }
#undef STAGE
#undef GLD

    // epilogue: lane holds D[row = wr*64+m*16+(l&15)][cols = wc*64+n*16+q*4 ..+3].
    // per m: XOR-swizzled LDS transpose of the wave's 16x64 slab -> 256B/row stores.
    float* rowbuf = (float*)&sA[0][0][0][0] + w * 1024;   // 16x64 floats per wave
    const int rr = l & 15;
    const float nr = norms[m0 + wr * 64 + 0 * 16 + rr];   // reloaded per m below
    (void)nr;
    #pragma unroll
    for (int m = 0; m < 4; ++m) {
        float nrm = norms[m0 + wr * 64 + m * 16 + rr];
        #pragma unroll
        for (int n = 0; n < 4; ++n) {
            int cb = n0 + wc * 64 + n * 16 + (q << 2);
            float4 ncv = *(const float4*)&norms[cb];
            f32x4 a = acc[m][n];
            float4 o;
            o.x = fmaxf(nrm + ncv.x - 2.0f * a[0], 0.0f);
            o.y = fmaxf(nrm + ncv.y - 2.0f * a[1], 0.0f);
            o.z = fmaxf(nrm + ncv.z - 2.0f * a[2], 0.0f);
            o.w = fmaxf(nrm + ncv.w - 2.0f * a[3], 0.0f);
            int ch = (n * 4 + q) ^ (rr & 7);
            *(float4*)(rowbuf + rr * 64 + ch * 4) = o;
        }
        #pragma unroll
        for (int s = 0; s < 4; ++s) {
            int row = s * 4 + q;
            int ch = (l & 15) ^ (row & 7);
            float4 v = *(const float4*)(rowbuf + row * 64 + ch * 4);
            *(float4*)&D[(size_t)(m0 + wr * 64 + m * 16 + row) * NT + n0 + wc * 64 + (l & 15) * 4] = v;
        }
    }
}

// ---------------------------------------------------------------- k_hist0_tri
// level-0 radix histogram (key>>22, 1024 bins) over triangle tiles.
__global__ __launch_bounds__(256) void k_hist0_tri(const float* __restrict__ D,
                                                   unsigned* __restrict__ gH)
{
    __shared__ unsigned h[1024];
    for (int i = threadIdx.x; i < 1024; i += 256) h[i] = 0;
    int bx, by;
    tri_map(blockIdx.x, bx, by);
    int m0 = by * 128, n0 = bx * 128;
    unsigned wt = (bx != by) ? 2u : 1u;
    int l = threadIdx.x & 63;
    __syncthreads();
    for (int v = threadIdx.x; v < 4096; v += 256) {
        int r = m0 + (v >> 5);
        int c0 = n0 + (v & 31) * 4;
        float4 dv = *(const float4*)&D[(size_t)r * NT + c0];
        const float* dd = (const float*)&dv;
        // per-lane merge of the 4 values (adjacent values often share a bin)
        unsigned pb = __float_as_uint(dd[0]) >> 22;
        unsigned pc = (r == c0) ? 0u : wt;
        #pragma unroll
        for (int j = 1; j < 4; ++j) {
            unsigned bj = __float_as_uint(dd[j]) >> 22;
            unsigned cj = (r == c0 + j) ? 0u : wt;
            if (bj == pb) pc += cj;
            else {
                if (pc) atomicAdd(&h[pb], pc);
                pb = bj; pc = cj;
            }
        }
        if (pc) atomicAdd(&h[pb], pc);
    }
    __syncthreads();
    for (int i = threadIdx.x; i < 1024; i += 256) {
        unsigned c = h[i];
        if (c) atomicAdd(&gH[i], c);
    }
}

// ---------------------------------------------------------------- k_scan0_beta
__global__ __launch_bounds__(64) void k_scan0_beta(const unsigned* __restrict__ hL0,
                                                   const float* __restrict__ g,
                                                   const float* __restrict__ beta_in,
                                                   unsigned* __restrict__ sel,
                                                   float* __restrict__ beta_out)
{
    int lane = threadIdx.x;
    for (int t = 0; t < 2; ++t) {
        unsigned r = sel[t * 2 + 1];
        unsigned s = 0;
        for (int i = 0; i < 16; ++i) s += hL0[lane * 16 + i];
        unsigned x = s;
        #pragma unroll
        for (int off = 1; off < 64; off <<= 1) {
            unsigned y = __shfl_up(x, off);
            if (lane >= off) x += y;
        }
        unsigned base = x - s;
        bool has = (r >= base) && (r < base + s);
        unsigned long long mm = __ballot(has);
        int leader = __ffsll(mm) - 1;
        unsigned bin = 0, cb = 0;
        if (lane == leader) {
            unsigned cc = base;
            for (int i = 0; i < 16; ++i) {
                unsigned hv = hL0[lane * 16 + i];
                if (r < cc + hv) { bin = lane * 16 + i; cb = cc; break; }
                cc += hv;
            }
        }
        bin = __shfl(bin, leader);
        cb = __shfl(cb, leader);
        if (lane == 0) {
            sel[t * 2 + 0] = bin;
            sel[t * 2 + 1] = r - cb;
        }
    }
    // ---- beta ----
    float gs[KN] = {0, 0, 0, 0, 0};
    float gg[15];
    #pragma unroll
    for (int i = 0; i < 15; ++i) gg[i] = 0.0f;
    for (int p = lane; p < 1024; p += 64) {
        float gv[KN];
        #pragma unroll
        for (int k = 0; k < KN; ++k) gv[k] = g[(size_t)p * KN + k];
        int idx = 0;
        #pragma unroll
        for (int a2 = 0; a2 < KN; ++a2) {
            gs[a2] += gv[a2];
            #pragma unroll
            for (int b2 = a2; b2 < KN; ++b2) gg[idx++] += gv[a2] * gv[b2];
        }
    }
    #pragma unroll
    for (int m = 32; m > 0; m >>= 1) {
        #pragma unroll
        for (int k = 0; k < KN; ++k) gs[k] += __shfl_xor(gs[k], m);
        #pragma unroll
        for (int i = 0; i < 15; ++i) gg[i] += __shfl_xor(gg[i], m);
    }
    if (lane == 0) {
        float Q[KN][KN], gm[KN];
        #pragma unroll
        for (int k = 0; k < KN; ++k) gm[k] = gs[k] * (1.0f / 1024.0f);
        int idx = 0;
        for (int a2 = 0; a2 < KN; ++a2)
            for (int b2 = a2; b2 < KN; ++b2) {
                float qv = gg[idx++] * (1.0f / 1024.0f) - gm[a2] * gm[b2];
                Q[a2][b2] = qv; Q[b2][a2] = qv;
            }
        for (int k = 0; k < KN; ++k) Q[k][k] += 0.001f;

        float b[KN], proj[KN];
        #pragma unroll
        for (int k = 0; k < KN; ++k) { b[k] = beta_in[k]; proj[k] = b[k]; }
        for (int it = 0; it < 100; ++it) {
            float v[KN];
            #pragma unroll
            for (int a2 = 0; a2 < KN; ++a2) {
                float qb = Q[a2][0] * b[0] + Q[a2][1] * b[1] + Q[a2][2] * b[2]
                         + Q[a2][3] * b[3] + Q[a2][4] * b[4];
                v[a2] = b[a2] - qb;
            }
            float mu[KN];
            #pragma unroll
            for (int k = 0; k < KN; ++k) mu[k] = v[k];
            // 9-comparator descending sort network
#define CMPSW(i, j) { float hi_ = fmaxf(mu[i], mu[j]); float lo_ = fminf(mu[i], mu[j]); mu[i] = hi_; mu[j] = lo_; }
            CMPSW(0,1) CMPSW(3,4) CMPSW(2,4) CMPSW(2,3) CMPSW(0,3) CMPSW(0,2) CMPSW(1,4) CMPSW(1,3) CMPSW(1,2)
#undef CMPSW
            float cs[KN]; cs[0] = mu[0];
            #pragma unroll
            for (int k = 1; k < KN; ++k) cs[k] = cs[k - 1] + mu[k];
            int rho = 0; bool anyc = false;
            #pragma unroll
            for (int k = 0; k < KN; ++k)
                if (mu[k] - (cs[k] - 1.0f) / (float)(k + 1) > 0.0f) { rho = k; anyc = true; }
            if (!anyc) rho = 0;
            float theta = (cs[rho] - 1.0f) / (float)(rho + 1);
            float ssum = 0;
            #pragma unroll
            for (int k = 0; k < KN; ++k) { proj[k] = fmaxf(v[k] - theta, 0.0f); ssum += proj[k]; }
            float invs = 1.0f / (ssum + 1e-12f);
            float nd = 0;
            #pragma unroll
            for (int k = 0; k < KN; ++k) {
                proj[k] *= invs;
                float dd = proj[k] - b[k];
                nd += dd * dd;
                b[k] = proj[k];
            }
            if (nd < 1e-12f) break;
        }
        #pragma unroll
        for (int k = 0; k < KN; ++k) beta_out[k] = proj[k];
    }
}

// ---------------------------------------------------------------- k_hist_tri (levels 1,2)
template<int LEVEL>
__global__ __launch_bounds__(256) void k_hist_tri(const float* __restrict__ D,
                                                  const unsigned* __restrict__ sel,
                                                  unsigned* __restrict__ gA,
                                                  unsigned* __restrict__ gB)
{
    constexpr int NB = (LEVEL == 2) ? 4096 : 1024;
    __shared__ unsigned lha[NB];
    __shared__ unsigned lhb[NB];
    for (int i = threadIdx.x; i < NB; i += 256) { lha[i] = 0; lhb[i] = 0; }
    unsigned pA = sel[0], pB = sel[2];
    int bx, by;
    tri_map(blockIdx.x, bx, by);
    int m0 = by * 128, n0 = bx * 128;
    unsigned wt = (bx != by) ? 2u : 1u;
    __syncthreads();
    for (int v = threadIdx.x; v < 4096; v += 256) {
        int r = m0 + (v >> 5);
        int c0 = n0 + (v & 31) * 4;
        float4 dv = *(const float4*)&D[(size_t)r * NT + c0];
        const float* dd = (const float*)&dv;
        #pragma unroll
        for (int j = 0; j < 4; ++j) {
            if (r == c0 + j) continue;
            unsigned key = __float_as_uint(dd[j]);
            if constexpr (LEVEL == 1) {
                if ((key >> 22) == pA) atomicAdd(&lha[(key >> 12) & 1023], wt);
                if ((key >> 22) == pB) atomicAdd(&lhb[(key >> 12) & 1023], wt);
            } else {
                if ((key >> 12) == pA) atomicAdd(&lha[key & 4095], wt);
                if ((key >> 12) == pB) atomicAdd(&lhb[key & 4095], wt);
            }
        }
    }
    __syncthreads();
    for (int i = threadIdx.x; i < NB; i += 256) {
        unsigned ca = lha[i];
        if (ca) atomicAdd(&gA[i], ca);
        unsigned cb = lhb[i];
        if (cb) atomicAdd(&gB[i], cb);
    }
}

// ---------------------------------------------------------------- k_scan (levels 1,2)
template<int LEVEL>
__global__ __launch_bounds__(64) void k_scan(const unsigned* __restrict__ hA,
                                             const unsigned* __restrict__ hB,
                                             unsigned* __restrict__ sel,
                                             float* __restrict__ params)
{
    constexpr int NB = (LEVEL == 2) ? 4096 : 1024;
    constexpr int C = NB / 64;
    int lane = threadIdx.x;
    for (int t = 0; t < 2; ++t) {
        const unsigned* h = (t == 0 ? hA : hB);
        unsigned r = sel[t * 2 + 1];
        unsigned s = 0;
        for (int i = 0; i < C; ++i) s += h[lane * C + i];
        unsigned x = s;
        #pragma unroll
        for (int off = 1; off < 64; off <<= 1) {
            unsigned y = __shfl_up(x, off);
            if (lane >= off) x += y;
        }
        unsigned base = x - s;
        bool has = (r >= base) && (r < base + s);
        unsigned long long mm = __ballot(has);
        int leader = __ffsll(mm) - 1;
        unsigned bin = 0, cb = 0;
        if (lane == leader) {
            unsigned cc = base;
            for (int i = 0; i < C; ++i) {
                unsigned hv = h[lane * C + i];
                if (r < cc + hv) { bin = lane * C + i; cb = cc; break; }
                cc += hv;
            }
        }
        bin = __shfl(bin, leader);
        cb = __shfl(cb, leader);
        if (lane == 0) {
            if (LEVEL == 1) sel[t * 2 + 0] = (sel[t * 2 + 0] << 10) | bin;
            else            sel[4 + t]     = (sel[t * 2 + 0] << 12) | bin;
            sel[t * 2 + 1] = r - cb;
        }
    }
    if (LEVEL == 2 && lane == 0) {
        float vA = __uint_as_float(sel[4]);
        float vB = __uint_as_float(sel[5]);
        float med = 0.5f * (vA + vB);
        float bw = (med + 1e-6f) * 0.25f;
        #pragma unroll
        for (int k = 0; k < KN; ++k) params[k] = 1.0f / (bw * (float)(1 << k));
    }
}

// ---------------------------------------------------------------- k_wsum_tri
__global__ __launch_bounds__(256) void k_wsum_tri(const float* __restrict__ D,
                                                  const float* __restrict__ params,
                                                  const float* __restrict__ beta,
                                                  double* __restrict__ partials)
{
    float i0 = params[0], i1 = params[1], i2 = params[2], i3 = params[3], i4 = params[4];
    float b0 = beta[0], b1 = beta[1], b2 = beta[2], b3 = beta[3], b4 = beta[4];
    const double wDiag = 1.0 / ((double)NS * (NS - 1));
    const double wOff = -1.0 / ((double)NS * NS);
    int bx, by;
    tri_map(blockIdx.x, bx, by);
    int m0 = by * 128, n0 = bx * 128;
    double wt = (bx != by) ? 2.0 : 1.0;
    double acc = 0.0;
    for (int v = threadIdx.x; v < 4096; v += 256) {
        int r = m0 + (v >> 5);
        int c0 = n0 + (v & 31) * 4;
        float4 dv = *(const float4*)&D[(size_t)r * NT + c0];
        const float* dd = (const float*)&dv;
        #pragma unroll
        for (int j = 0; j < 4; ++j) {
            int c = c0 + j;
            if (r == c) continue;
            float sq = dd[j];
            float val = b0 * __expf(-sq * i0) + b1 * __expf(-sq * i1) + b2 * __expf(-sq * i2)
                      + b3 * __expf(-sq * i3) + b4 * __expf(-sq * i4);
            bool same = (r < NS) == (c < NS);
            acc += (same ? wDiag : wOff) * (double)val;
        }
    }
    acc *= wt;
    __shared__ double red[256];
    red[threadIdx.x] = acc;
    __syncthreads();
    for (int off = 128; off > 0; off >>= 1) {
        if (threadIdx.x < off) red[threadIdx.x] += red[threadIdx.x + off];
        __syncthreads();
    }
    if (threadIdx.x == 0) partials[blockIdx.x] = red[0];
}

// ---------------------------------------------------------------- k_final
__global__ __launch_bounds__(256) void k_final(const double* __restrict__ partials,
                                               float* __restrict__ out, int count)
{
    double acc = 0;
    for (int i = threadIdx.x; i < count; i += 256) acc += partials[i];
    __shared__ double red[256];
    red[threadIdx.x] = acc;
    __syncthreads();
    for (int off = 128; off > 0; off >>= 1) {
        if (threadIdx.x < off) red[threadIdx.x] += red[threadIdx.x + off];
        __syncthreads();
    }
    if (threadIdx.x == 0) out[0] = (float)fmax(red[0], 0.0);
}

// ---------------------------------------------------------------- launch
extern "C" void kernel_launch(void* const* d_in, const int* in_sizes, int n_in,
                              void* d_out, int out_size, void* d_ws, size_t ws_size,
                              hipStream_t stream)
{
    const float* S = (const float*)d_in[0];
    const float* T = (const float*)d_in[1];
    const float* beta = (const float*)d_in[2];
    float* out = (float*)d_out;

    float* D = (float*)d_ws;                              // 4096*4096 f
    unsigned short* Hi = (unsigned short*)(D + (size_t)NT * NT);
    unsigned short* Lo = Hi + (size_t)NT * DDIM;
    float* norms = (float*)(Lo + (size_t)NT * DDIM);      // 4096 f
    float* g = norms + NT;                                // 5120 f
    float* beta2 = g + 1024 * KN;                         // 8 f
    float* params = beta2 + 8;                            // 8 f
    unsigned* sel = (unsigned*)(params + 8);              // 16 u
    unsigned* hists = sel + 16;                           // 11264 u
    unsigned* hL0 = hists;
    unsigned* hL1A = hL0 + 1024;
    unsigned* hL1B = hL1A + 1024;
    unsigned* hL2A = hL1B + 1024;
    unsigned* hL2B = hL2A + 4096;
    double* partials = (double*)(hists + 11264);          // 528 d

    k_prep2<<<dim3(256), dim3(256), 0, stream>>>(S, T, Hi, Lo, norms, g, hists, sel);
    k_dist_mfma<<<dim3(NTILES), dim3(256), 0, stream>>>(Hi, Lo, norms, D);
    k_hist0_tri<<<dim3(NTILES), dim3(256), 0, stream>>>(D, hL0);
    k_scan0_beta<<<dim3(1), dim3(64), 0, stream>>>(hL0, g, beta, sel, beta2);
    k_hist_tri<1><<<dim3(NTILES), dim3(256), 0, stream>>>(D, sel, hL1A, hL1B);
    k_scan<1><<<dim3(1), dim3(64), 0, stream>>>(hL1A, hL1B, sel, params);
    k_hist_tri<2><<<dim3(NTILES), dim3(256), 0, stream>>>(D, sel, hL2A, hL2B);
    k_scan<2><<<dim3(1), dim3(64), 0, stream>>>(hL2A, hL2B, sel, params);
    k_wsum_tri<<<dim3(NTILES), dim3(256), 0, stream>>>(D, params, beta2, partials);
    k_final<<<dim3(1), dim3(256), 0, stream>>>(partials, out, NTILES);
}

// Round 5
// 151.670 us; speedup vs baseline: 3.4929x; 1.2698x over previous
//
#include <hip/hip_runtime.h>
#include <math.h>

#define NT 4096
#define NS 2048
#define DDIM 512
#define KN 5
#define NTILES 528   // 32*33/2 triangle tiles of 128x128

typedef __bf16 bf16x8 __attribute__((ext_vector_type(8)));
typedef float f32x4 __attribute__((ext_vector_type(4)));
typedef unsigned short u16x8 __attribute__((ext_vector_type(8)));

static __device__ inline unsigned short f2bf(float x) {
    unsigned u = __float_as_uint(x);
    unsigned r = (u + 0x7fffu + ((u >> 16) & 1u)) >> 16;
    return (unsigned short)r;
}
static __device__ inline float bf2f(unsigned short h) {
    return __uint_as_float(((unsigned)h) << 16);
}

static __device__ inline void tri_map(int b, int& bx, int& by) {
    int x = (int)((sqrtf(8.0f * (float)b + 1.0f) - 1.0f) * 0.5f);
    while ((x + 1) * (x + 2) / 2 <= b) ++x;
    while (x * (x + 1) / 2 > b) --x;
    bx = x;
    by = b - x * (x + 1) / 2;
}

// ---------------------------------------------------------------- beta solve
// division-free per-iteration simplex projection; runs on one wave (lane 0 serial part).
static __device__ void beta_solve(const float* __restrict__ g,
                                  const float* __restrict__ beta_in,
                                  float* __restrict__ beta_out)
{
    int lane = threadIdx.x;
    float gs[KN] = {0, 0, 0, 0, 0};
    float gg[15];
    #pragma unroll
    for (int i = 0; i < 15; ++i) gg[i] = 0.0f;
    for (int p = lane; p < 1024; p += 64) {
        float gv[KN];
        #pragma unroll
        for (int k = 0; k < KN; ++k) gv[k] = g[(size_t)p * KN + k];
        int idx = 0;
        #pragma unroll
        for (int a2 = 0; a2 < KN; ++a2) {
            gs[a2] += gv[a2];
            #pragma unroll
            for (int b2 = a2; b2 < KN; ++b2) gg[idx++] += gv[a2] * gv[b2];
        }
    }
    #pragma unroll
    for (int m = 32; m > 0; m >>= 1) {
        #pragma unroll
        for (int k = 0; k < KN; ++k) gs[k] += __shfl_xor(gs[k], m);
        #pragma unroll
        for (int i = 0; i < 15; ++i) gg[i] += __shfl_xor(gg[i], m);
    }
    if (lane != 0) return;

    float Q[KN][KN], gm[KN];
    #pragma unroll
    for (int k = 0; k < KN; ++k) gm[k] = gs[k] * (1.0f / 1024.0f);
    int idx = 0;
    #pragma unroll
    for (int a2 = 0; a2 < KN; ++a2)
        #pragma unroll
        for (int b2 = a2; b2 < KN; ++b2) {
            float qv = gg[idx++] * (1.0f / 1024.0f) - gm[a2] * gm[b2];
            Q[a2][b2] = qv; Q[b2][a2] = qv;
        }
    #pragma unroll
    for (int k = 0; k < KN; ++k) Q[k][k] += 0.001f;

    float b[KN], proj[KN];
    #pragma unroll
    for (int k = 0; k < KN; ++k) { b[k] = beta_in[k]; proj[k] = b[k]; }
    for (int it = 0; it < 100; ++it) {
        float v[KN];
        #pragma unroll
        for (int a2 = 0; a2 < KN; ++a2) {
            float qb = Q[a2][0] * b[0] + Q[a2][1] * b[1] + Q[a2][2] * b[2]
                     + Q[a2][3] * b[3] + Q[a2][4] * b[4];
            v[a2] = b[a2] - qb;
        }
        float mu0 = v[0], mu1 = v[1], mu2 = v[2], mu3 = v[3], mu4 = v[4];
        // 9-comparator descending sort network
#define CMPSW(x, y) { float hi_ = fmaxf(x, y); float lo_ = fminf(x, y); x = hi_; y = lo_; }
        CMPSW(mu0, mu1) CMPSW(mu3, mu4) CMPSW(mu2, mu4) CMPSW(mu2, mu3)
        CMPSW(mu0, mu3) CMPSW(mu0, mu2) CMPSW(mu1, mu4) CMPSW(mu1, mu3) CMPSW(mu1, mu2)
#undef CMPSW
        float cs0 = mu0, cs1 = cs0 + mu1, cs2 = cs1 + mu2, cs3 = cs2 + mu3, cs4 = cs3 + mu4;
        // cond_k <=> mu_k - (cs_k-1)/(k+1) > 0 <=> mu_k*(k+1) > cs_k-1  (no division)
        bool c1 = mu1 * 2.0f > cs1 - 1.0f;
        bool c2 = mu2 * 3.0f > cs2 - 1.0f;
        bool c3 = mu3 * 4.0f > cs3 - 1.0f;
        bool c4 = mu4 * 5.0f > cs4 - 1.0f;
        float csSel = cs0, rcpSel = 1.0f;            // rho defaults to 0
        if (c1) { csSel = cs1; rcpSel = 0.5f; }
        if (c2) { csSel = cs2; rcpSel = (1.0f / 3.0f); }
        if (c3) { csSel = cs3; rcpSel = 0.25f; }
        if (c4) { csSel = cs4; rcpSel = 0.2f; }
        float theta = (csSel - 1.0f) * rcpSel;
        float ssum = 0.0f;
        #pragma unroll
        for (int k = 0; k < KN; ++k) { proj[k] = fmaxf(v[k] - theta, 0.0f); ssum += proj[k]; }
        float invs = 1.0f / (ssum + 1e-12f);
        float nd = 0.0f;
        #pragma unroll
        for (int k = 0; k < KN; ++k) {
            proj[k] *= invs;
            float dd = proj[k] - b[k];
            nd += dd * dd;
            b[k] = proj[k];
        }
        if (nd < 1e-12f) break;
    }
    #pragma unroll
    for (int k = 0; k < KN; ++k) beta_out[k] = proj[k];
}

// ---------------------------------------------------------------- k_prep2
// fused: bf16 hi/lo split + row norms + per-pair g matrix + hist/sel init.
__global__ __launch_bounds__(256) void k_prep2(const float* __restrict__ S,
                                               const float* __restrict__ T,
                                               unsigned short* __restrict__ Hi,
                                               unsigned short* __restrict__ Lo,
                                               float* __restrict__ norms,
                                               float* __restrict__ g,
                                               unsigned* __restrict__ hists,
                                               unsigned* __restrict__ sel)
{
    if (blockIdx.x < 44) hists[blockIdx.x * 256 + threadIdx.x] = 0;  // 44*256=11264
    if (blockIdx.x == 50 && threadIdx.x == 0) {
        sel[0] = 0u; sel[1] = 8386559u;          // middle ranks of 4096*4095
        sel[2] = 0u; sel[3] = 8386560u;
    }
    int p = blockIdx.x * 4 + (threadIdx.x >> 6);
    int l = threadIdx.x & 63;
    const float* r0 = S + (size_t)(2 * p) * DDIM;
    const float* r1 = r0 + DDIM;
    const float* r2 = T + (size_t)(2 * p) * DDIM;
    const float* r3 = r2 + DDIM;
    float a[8], b[8], c[8], d[8];
    *(float4*)&a[0] = *(const float4*)(r0 + l * 8); *(float4*)&a[4] = *(const float4*)(r0 + l * 8 + 4);
    *(float4*)&b[0] = *(const float4*)(r1 + l * 8); *(float4*)&b[4] = *(const float4*)(r1 + l * 8 + 4);
    *(float4*)&c[0] = *(const float4*)(r2 + l * 8); *(float4*)&c[4] = *(const float4*)(r2 + l * 8 + 4);
    *(float4*)&d[0] = *(const float4*)(r3 + l * 8); *(float4*)&d[4] = *(const float4*)(r3 + l * 8 + 4);

    float n0 = 0, n1 = 0, n2 = 0, n3 = 0;
    float s01 = 0, s23 = 0, s02 = 0, s13 = 0, s03 = 0, s12 = 0;
    u16x8 h0, l0, h1, l1, h2, l2, h3, l3;
    #pragma unroll
    for (int k = 0; k < 8; ++k) {
        float va = a[k], vb = b[k], vc = c[k], vd = d[k];
        n0 += va * va; n1 += vb * vb; n2 += vc * vc; n3 += vd * vd;
        float t01 = va - vb, t23 = vc - vd, t02 = va - vc, t13 = vb - vd;
        s01 += t01*t01; s23 += t23*t23; s02 += t02*t02; s13 += t13*t13;
        float t03 = va - vd, t12 = vb - vc;
        s03 += t03*t03; s12 += t12*t12;
        unsigned short hh;
        hh = f2bf(va); h0[k] = hh; l0[k] = f2bf(va - bf2f(hh));
        hh = f2bf(vb); h1[k] = hh; l1[k] = f2bf(vb - bf2f(hh));
        hh = f2bf(vc); h2[k] = hh; l2[k] = f2bf(vc - bf2f(hh));
        hh = f2bf(vd); h3[k] = hh; l3[k] = f2bf(vd - bf2f(hh));
    }
    size_t g0 = (size_t)(2 * p) * DDIM + l * 8;
    size_t g1 = g0 + DDIM;
    size_t g2 = (size_t)(NS + 2 * p) * DDIM + l * 8;
    size_t g3 = g2 + DDIM;
    *(u16x8*)&Hi[g0] = h0; *(u16x8*)&Lo[g0] = l0;
    *(u16x8*)&Hi[g1] = h1; *(u16x8*)&Lo[g1] = l1;
    *(u16x8*)&Hi[g2] = h2; *(u16x8*)&Lo[g2] = l2;
    *(u16x8*)&Hi[g3] = h3; *(u16x8*)&Lo[g3] = l3;

    #pragma unroll
    for (int m = 32; m > 0; m >>= 1) {
        n0 += __shfl_xor(n0, m); n1 += __shfl_xor(n1, m);
        n2 += __shfl_xor(n2, m); n3 += __shfl_xor(n3, m);
        s01 += __shfl_xor(s01, m); s23 += __shfl_xor(s23, m);
        s02 += __shfl_xor(s02, m); s13 += __shfl_xor(s13, m);
        s03 += __shfl_xor(s03, m); s12 += __shfl_xor(s12, m);
    }
    if (l == 0) {
        norms[2 * p] = n0; norms[2 * p + 1] = n1;
        norms[NS + 2 * p] = n2; norms[NS + 2 * p + 1] = n3;
        float v[6] = { s01, s02, s03, s12, s13, s23 };
        for (int i = 0; i < 5; ++i)
            for (int j = 0; j < 5 - i; ++j)
                if (v[j] > v[j + 1]) { float t = v[j]; v[j] = v[j + 1]; v[j + 1] = t; }
        float med = 0.5f * (v[2] + v[3]);
        float bw = (med + 1e-6f) * 0.25f;
        #pragma unroll
        for (int k = 0; k < KN; ++k) {
            float inv = 1.0f / (bw * (float)(1 << k));
            g[(size_t)p * KN + k] = expf(-s01 * inv) + expf(-s23 * inv)
                                  - expf(-s02 * inv) - expf(-s13 * inv);
        }
    }
}

// ---------------------------------------------------------------- k_dist_mfma
// block 0: beta fixed-point (concurrent, off critical path).
// blocks 1..528: upper-triangle 128x128 tiles of D via split-bf16 MFMA,
// dbuf LDS, operand-swapped MFMA, LDS-transposed full-row float4 stores.
__global__ __launch_bounds__(256) void k_dist_mfma(const unsigned short* __restrict__ Hi,
                                                   const unsigned short* __restrict__ Lo,
                                                   const float* __restrict__ norms,
                                                   float* __restrict__ D,
                                                   const float* __restrict__ g,
                                                   const float* __restrict__ beta_in,
                                                   float* __restrict__ beta_out)
{
    __shared__ __align__(16) unsigned short sA[2][2][128][32];  // [buf][plane][row][col]
    __shared__ __align__(16) unsigned short sB[2][2][128][32];

    if (blockIdx.x == 0) {
        if (threadIdx.x < 64) beta_solve(g, beta_in, beta_out);
        return;
    }

    int bb = blockIdx.x - 1;
    int swz = (bb & 7) * 66 + (bb >> 3);         // 528 = 8*66, bijective XCD swizzle
    int bx, by;
    tri_map(swz, bx, by);
    const int m0 = by * 128, n0 = bx * 128;

    const int tid = threadIdx.x;
    const int w = tid >> 6, l = tid & 63;
    const int wr = w >> 1, wc = w & 1;

    // staging: lane covers row (w*16 + l/4), slot (l&3); swizzle f(r)=((r&3)+((r>>2)&3))&3
    const int chunk = (l & 3) ^ ((((l >> 2) & 3) + ((l >> 4) & 3)) & 3);
    const size_t gA0 = (size_t)(m0 + w * 16 + (l >> 2)) * DDIM + chunk * 8;
    const size_t gA1 = gA0 + (size_t)64 * DDIM;
    const size_t gB0 = (size_t)(n0 + w * 16 + (l >> 2)) * DDIM + chunk * 8;
    const size_t gB1 = gB0 + (size_t)64 * DDIM;
    const unsigned w1024 = w * 1024;

#define GLD(dst, srcptr, goff)                                                      \
    __builtin_amdgcn_global_load_lds(                                               \
        (const __attribute__((address_space(1))) unsigned*)((srcptr) + (goff)),     \
        (__attribute__((address_space(3))) unsigned*)((char*)(dst) + w1024), 16, 0, 0)
#define STAGE(buf, kk)                                  \
    do {                                                \
        GLD(&sA[buf][0][0][0],  Hi, gA0 + (kk));        \
        GLD(&sA[buf][0][64][0], Hi, gA1 + (kk));        \
        GLD(&sA[buf][1][0][0],  Lo, gA0 + (kk));        \
        GLD(&sA[buf][1][64][0], Lo, gA1 + (kk));        \
        GLD(&sB[buf][0][0][0],  Hi, gB0 + (kk));        \
        GLD(&sB[buf][0][64][0], Hi, gB1 + (kk));        \
        GLD(&sB[buf][1][0][0],  Lo, gB0 + (kk));        \
        GLD(&sB[buf][1][64][0], Lo, gB1 + (kk));        \
    } while (0)

    f32x4 acc[4][4] = {};
    const int q = l >> 4;
    const int fr = ((l & 3) + ((l >> 2) & 3)) & 3;
    const unsigned soff = ((unsigned)(q ^ fr)) << 4;
    const unsigned rowbA = (wr * 64 + (l & 15)) * 64 + soff;
    const unsigned rowbB = (wc * 64 + (l & 15)) * 64 + soff;

    STAGE(0, 0);
    __syncthreads();

    #pragma unroll 2
    for (int t = 0; t < 16; ++t) {
        const int cur = t & 1;
        if (t < 15) STAGE(cur ^ 1, (t + 1) * 32);

        bf16x8 ah[4], al[4], bh[4], bl[4];
        #pragma unroll
        for (int m = 0; m < 4; ++m) {
            ah[m] = *(const bf16x8*)((const char*)&sA[cur][0][0][0] + rowbA + m * 1024);
            al[m] = *(const bf16x8*)((const char*)&sA[cur][1][0][0] + rowbA + m * 1024);
        }
        #pragma unroll
        for (int n = 0; n < 4; ++n) {
            bh[n] = *(const bf16x8*)((const char*)&sB[cur][0][0][0] + rowbB + n * 1024);
            bl[n] = *(const bf16x8*)((const char*)&sB[cur][1][0][0] + rowbB + n * 1024);
        }
        // operand-swapped: first operand = B rows -> acc reg indexes D columns
        #pragma unroll
        for (int m = 0; m < 4; ++m)
            #pragma unroll
            for (int n = 0; n < 4; ++n) {
                acc[m][n] = __builtin_amdgcn_mfma_f32_16x16x32_bf16(bh[n], ah[m], acc[m][n], 0, 0, 0);
                acc[m][n] = __builtin_amdgcn_mfma_f32_16x16x32_bf16(bl[n], ah[m], acc[m][n], 0, 0, 0);
                acc[m][n] = __builtin_amdgcn_mfma_f32_16x16x32_bf16(bh[n], al[m], acc[m][n], 0, 0, 0);
            }
        __syncthreads();
    }
#undef STAGE
#undef GLD

    // epilogue: lane holds D[row = wr*64+m*16+(l&15)][cols = wc*64+n*16+q*4 ..+3].
    // per m: XOR-swizzled LDS transpose of the wave's 16x64 slab -> 256B/row stores.
    float* rowbuf = (float*)&sA[0][0][0][0] + w * 1024;   // 16x64 floats per wave
    const int rr = l & 15;
    #pragma unroll
    for (int m = 0; m < 4; ++m) {
        float nrm = norms[m0 + wr * 64 + m * 16 + rr];
        #pragma unroll
        for (int n = 0; n < 4; ++n) {
            int cb = n0 + wc * 64 + n * 16 + (q << 2);
            float4 ncv = *(const float4*)&norms[cb];
            f32x4 a = acc[m][n];
            float4 o;
            o.x = fmaxf(nrm + ncv.x - 2.0f * a[0], 0.0f);
            o.y = fmaxf(nrm + ncv.y - 2.0f * a[1], 0.0f);
            o.z = fmaxf(nrm + ncv.z - 2.0f * a[2], 0.0f);
            o.w = fmaxf(nrm + ncv.w - 2.0f * a[3], 0.0f);
            int ch = (n * 4 + q) ^ (rr & 7);
            *(float4*)(rowbuf + rr * 64 + ch * 4) = o;
        }
        #pragma unroll
        for (int s = 0; s < 4; ++s) {
            int row = s * 4 + q;
            int ch = (l & 15) ^ (row & 7);
            float4 v = *(const float4*)(rowbuf + row * 64 + ch * 4);
            *(float4*)&D[(size_t)(m0 + wr * 64 + m * 16 + row) * NT + n0 + wc * 64 + (l & 15) * 4] = v;
        }
    }
}

// ---------------------------------------------------------------- k_hist0_tri
// level-0 radix histogram (key>>22, 1024 bins) over triangle tiles.
__global__ __launch_bounds__(256) void k_hist0_tri(const float* __restrict__ D,
                                                   unsigned* __restrict__ gH)
{
    __shared__ unsigned h[1024];
    for (int i = threadIdx.x; i < 1024; i += 256) h[i] = 0;
    int bx, by;
    tri_map(blockIdx.x, bx, by);
    int m0 = by * 128, n0 = bx * 128;
    unsigned wt = (bx != by) ? 2u : 1u;
    __syncthreads();
    for (int v = threadIdx.x; v < 4096; v += 256) {
        int r = m0 + (v >> 5);
        int c0 = n0 + (v & 31) * 4;
        float4 dv = *(const float4*)&D[(size_t)r * NT + c0];
        const float* dd = (const float*)&dv;
        unsigned pb = __float_as_uint(dd[0]) >> 22;
        unsigned pc = (r == c0) ? 0u : wt;
        #pragma unroll
        for (int j = 1; j < 4; ++j) {
            unsigned bj = __float_as_uint(dd[j]) >> 22;
            unsigned cj = (r == c0 + j) ? 0u : wt;
            if (bj == pb) pc += cj;
            else {
                if (pc) atomicAdd(&h[pb], pc);
                pb = bj; pc = cj;
            }
        }
        if (pc) atomicAdd(&h[pb], pc);
    }
    __syncthreads();
    for (int i = threadIdx.x; i < 1024; i += 256) {
        unsigned c = h[i];
        if (c) atomicAdd(&gH[i], c);
    }
}

// ---------------------------------------------------------------- k_scan0
__global__ __launch_bounds__(64) void k_scan0(const unsigned* __restrict__ hL0,
                                              unsigned* __restrict__ sel)
{
    int lane = threadIdx.x;
    for (int t = 0; t < 2; ++t) {
        unsigned r = sel[t * 2 + 1];
        unsigned s = 0;
        for (int i = 0; i < 16; ++i) s += hL0[lane * 16 + i];
        unsigned x = s;
        #pragma unroll
        for (int off = 1; off < 64; off <<= 1) {
            unsigned y = __shfl_up(x, off);
            if (lane >= off) x += y;
        }
        unsigned base = x - s;
        bool has = (r >= base) && (r < base + s);
        unsigned long long mm = __ballot(has);
        int leader = __ffsll(mm) - 1;
        unsigned bin = 0, cb = 0;
        if (lane == leader) {
            unsigned cc = base;
            for (int i = 0; i < 16; ++i) {
                unsigned hv = hL0[lane * 16 + i];
                if (r < cc + hv) { bin = lane * 16 + i; cb = cc; break; }
                cc += hv;
            }
        }
        bin = __shfl(bin, leader);
        cb = __shfl(cb, leader);
        if (lane == 0) {
            sel[t * 2 + 0] = bin;
            sel[t * 2 + 1] = r - cb;
        }
    }
}

// ---------------------------------------------------------------- k_hist_tri (levels 1,2)
template<int LEVEL>
__global__ __launch_bounds__(256) void k_hist_tri(const float* __restrict__ D,
                                                  const unsigned* __restrict__ sel,
                                                  unsigned* __restrict__ gA,
                                                  unsigned* __restrict__ gB)
{
    constexpr int NB = (LEVEL == 2) ? 4096 : 1024;
    __shared__ unsigned lha[NB];
    __shared__ unsigned lhb[NB];
    for (int i = threadIdx.x; i < NB; i += 256) { lha[i] = 0; lhb[i] = 0; }
    unsigned pA = sel[0], pB = sel[2];
    int bx, by;
    tri_map(blockIdx.x, bx, by);
    int m0 = by * 128, n0 = bx * 128;
    unsigned wt = (bx != by) ? 2u : 1u;
    __syncthreads();
    for (int v = threadIdx.x; v < 4096; v += 256) {
        int r = m0 + (v >> 5);
        int c0 = n0 + (v & 31) * 4;
        float4 dv = *(const float4*)&D[(size_t)r * NT + c0];
        const float* dd = (const float*)&dv;
        #pragma unroll
        for (int j = 0; j < 4; ++j) {
            if (r == c0 + j) continue;
            unsigned key = __float_as_uint(dd[j]);
            if constexpr (LEVEL == 1) {
                if ((key >> 22) == pA) atomicAdd(&lha[(key >> 12) & 1023], wt);
                if ((key >> 22) == pB) atomicAdd(&lhb[(key >> 12) & 1023], wt);
            } else {
                if ((key >> 12) == pA) atomicAdd(&lha[key & 4095], wt);
                if ((key >> 12) == pB) atomicAdd(&lhb[key & 4095], wt);
            }
        }
    }
    __syncthreads();
    for (int i = threadIdx.x; i < NB; i += 256) {
        unsigned ca = lha[i];
        if (ca) atomicAdd(&gA[i], ca);
        unsigned cb = lhb[i];
        if (cb) atomicAdd(&gB[i], cb);
    }
}

// ---------------------------------------------------------------- k_scan (levels 1,2)
template<int LEVEL>
__global__ __launch_bounds__(64) void k_scan(const unsigned* __restrict__ hA,
                                             const unsigned* __restrict__ hB,
                                             unsigned* __restrict__ sel,
                                             float* __restrict__ params)
{
    constexpr int NB = (LEVEL == 2) ? 4096 : 1024;
    constexpr int C = NB / 64;
    int lane = threadIdx.x;
    for (int t = 0; t < 2; ++t) {
        const unsigned* h = (t == 0 ? hA : hB);
        unsigned r = sel[t * 2 + 1];
        unsigned s = 0;
        for (int i = 0; i < C; ++i) s += h[lane * C + i];
        unsigned x = s;
        #pragma unroll
        for (int off = 1; off < 64; off <<= 1) {
            unsigned y = __shfl_up(x, off);
            if (lane >= off) x += y;
        }
        unsigned base = x - s;
        bool has = (r >= base) && (r < base + s);
        unsigned long long mm = __ballot(has);
        int leader = __ffsll(mm) - 1;
        unsigned bin = 0, cb = 0;
        if (lane == leader) {
            unsigned cc = base;
            for (int i = 0; i < C; ++i) {
                unsigned hv = h[lane * C + i];
                if (r < cc + hv) { bin = lane * C + i; cb = cc; break; }
                cc += hv;
            }
        }
        bin = __shfl(bin, leader);
        cb = __shfl(cb, leader);
        if (lane == 0) {
            if (LEVEL == 1) sel[t * 2 + 0] = (sel[t * 2 + 0] << 10) | bin;
            else            sel[4 + t]     = (sel[t * 2 + 0] << 12) | bin;
            sel[t * 2 + 1] = r - cb;
        }
    }
    if (LEVEL == 2 && lane == 0) {
        float vA = __uint_as_float(sel[4]);
        float vB = __uint_as_float(sel[5]);
        float med = 0.5f * (vA + vB);
        float bw = (med + 1e-6f) * 0.25f;
        #pragma unroll
        for (int k = 0; k < KN; ++k) params[k] = 1.0f / (bw * (float)(1 << k));
    }
}

// ---------------------------------------------------------------- k_wsum_tri
__global__ __launch_bounds__(256) void k_wsum_tri(const float* __restrict__ D,
                                                  const float* __restrict__ params,
                                                  const float* __restrict__ beta,
                                                  double* __restrict__ partials)
{
    float i0 = params[0], i1 = params[1], i2 = params[2], i3 = params[3], i4 = params[4];
    float b0 = beta[0], b1 = beta[1], b2 = beta[2], b3 = beta[3], b4 = beta[4];
    const double wDiag = 1.0 / ((double)NS * (NS - 1));
    const double wOff = -1.0 / ((double)NS * NS);
    int bx, by;
    tri_map(blockIdx.x, bx, by);
    int m0 = by * 128, n0 = bx * 128;
    double wt = (bx != by) ? 2.0 : 1.0;
    double acc = 0.0;
    for (int v = threadIdx.x; v < 4096; v += 256) {
        int r = m0 + (v >> 5);
        int c0 = n0 + (v & 31) * 4;
        float4 dv = *(const float4*)&D[(size_t)r * NT + c0];
        const float* dd = (const float*)&dv;
        #pragma unroll
        for (int j = 0; j < 4; ++j) {
            int c = c0 + j;
            if (r == c) continue;
            float sq = dd[j];
            float val = b0 * __expf(-sq * i0) + b1 * __expf(-sq * i1) + b2 * __expf(-sq * i2)
                      + b3 * __expf(-sq * i3) + b4 * __expf(-sq * i4);
            bool same = (r < NS) == (c < NS);
            acc += (same ? wDiag : wOff) * (double)val;
        }
    }
    acc *= wt;
    __shared__ double red[256];
    red[threadIdx.x] = acc;
    __syncthreads();
    for (int off = 128; off > 0; off >>= 1) {
        if (threadIdx.x < off) red[threadIdx.x] += red[threadIdx.x + off];
        __syncthreads();
    }
    if (threadIdx.x == 0) partials[blockIdx.x] = red[0];
}

// ---------------------------------------------------------------- k_final
__global__ __launch_bounds__(256) void k_final(const double* __restrict__ partials,
                                               float* __restrict__ out, int count)
{
    double acc = 0;
    for (int i = threadIdx.x; i < count; i += 256) acc += partials[i];
    __shared__ double red[256];
    red[threadIdx.x] = acc;
    __syncthreads();
    for (int off = 128; off > 0; off >>= 1) {
        if (threadIdx.x < off) red[threadIdx.x] += red[threadIdx.x + off];
        __syncthreads();
    }
    if (threadIdx.x == 0) out[0] = (float)fmax(red[0], 0.0);
}

// ---------------------------------------------------------------- launch
extern "C" void kernel_launch(void* const* d_in, const int* in_sizes, int n_in,
                              void* d_out, int out_size, void* d_ws, size_t ws_size,
                              hipStream_t stream)
{
    const float* S = (const float*)d_in[0];
    const float* T = (const float*)d_in[1];
    const float* beta = (const float*)d_in[2];
    float* out = (float*)d_out;

    float* D = (float*)d_ws;                              // 4096*4096 f
    unsigned short* Hi = (unsigned short*)(D + (size_t)NT * NT);
    unsigned short* Lo = Hi + (size_t)NT * DDIM;
    float* norms = (float*)(Lo + (size_t)NT * DDIM);      // 4096 f
    float* g = norms + NT;                                // 5120 f
    float* beta2 = g + 1024 * KN;                         // 8 f
    float* params = beta2 + 8;                            // 8 f
    unsigned* sel = (unsigned*)(params + 8);              // 16 u
    unsigned* hists = sel + 16;                           // 11264 u
    unsigned* hL0 = hists;
    unsigned* hL1A = hL0 + 1024;
    unsigned* hL1B = hL1A + 1024;
    unsigned* hL2A = hL1B + 1024;
    unsigned* hL2B = hL2A + 4096;
    double* partials = (double*)(hists + 11264);          // 528 d

    k_prep2<<<dim3(256), dim3(256), 0, stream>>>(S, T, Hi, Lo, norms, g, hists, sel);
    k_dist_mfma<<<dim3(NTILES + 1), dim3(256), 0, stream>>>(Hi, Lo, norms, D, g, beta, beta2);
    k_hist0_tri<<<dim3(NTILES), dim3(256), 0, stream>>>(D, hL0);
    k_scan0<<<dim3(1), dim3(64), 0, stream>>>(hL0, sel);
    k_hist_tri<1><<<dim3(NTILES), dim3(256), 0, stream>>>(D, sel, hL1A, hL1B);
    k_scan<1><<<dim3(1), dim3(64), 0, stream>>>(hL1A, hL1B, sel, params);
    k_hist_tri<2><<<dim3(NTILES), dim3(256), 0, stream>>>(D, sel, hL2A, hL2B);
    k_scan<2><<<dim3(1), dim3(64), 0, stream>>>(hL2A, hL2B, sel, params);
    k_wsum_tri<<<dim3(NTILES), dim3(256), 0, stream>>>(D, params, beta2, partials);
    k_final<<<dim3(1), dim3(256), 0, stream>>>(partials, out, NTILES);
}